// Round 10
// baseline (446.288 us; speedup 1.0000x reference)
//
#include <hip/hip_runtime.h>
#include <hip/hip_fp16.h>

#define NN 50000
#define NE 800000
#define NG 64
#define NC 10
#define BN_EPS 1e-5f
#define NSB 196   // ceil(NN/256)

typedef __attribute__((ext_vector_type(2))) _Float16 h2v;
typedef __attribute__((ext_vector_type(8))) _Float16 f16x8;
typedef __attribute__((ext_vector_type(4))) float f32x4;

__device__ __forceinline__ float2 up2(unsigned u) {
    __half2 h = *reinterpret_cast<__half2*>(&u);
    return __half22float2(h);
}
__device__ __forceinline__ unsigned pk2(float a, float b) {
    __half2 h = __floats2half2_rn(a, b);
    return *reinterpret_cast<unsigned*>(&h);
}
__device__ __forceinline__ float fdot2u(unsigned a, unsigned b, float c) {
    return __builtin_amdgcn_fdot2(__builtin_bit_cast(h2v, a), __builtin_bit_cast(h2v, b), c, false);
}

// ---------------- CSR build ----------------

__global__ void deg_count_kernel(const int* __restrict__ dst, int* __restrict__ deg,
                                 unsigned short* __restrict__ pos16) {
    int e = blockIdx.x * blockDim.x + threadIdx.x;
    if (e < NE) {
        int d = __builtin_nontemporal_load(&dst[e]);
        unsigned short p = (unsigned short)atomicAdd(&deg[d], 1);
        __builtin_nontemporal_store(p, &pos16[e]);
    }
}

__global__ __launch_bounds__(256) void block_sum_kernel(const int* __restrict__ deg,
                                                        int* __restrict__ bsum) {
    int b = blockIdx.x, t = threadIdx.x;
    int n = b * 256 + t;
    int v = (n < NN) ? deg[n] : 0;
    __shared__ int red[256];
    red[t] = v;
    __syncthreads();
    for (int off = 128; off > 0; off >>= 1) {
        if (t < off) red[t] += red[t + off];
        __syncthreads();
    }
    if (t == 0) bsum[b] = red[0];
}

__global__ __launch_bounds__(256) void bsum_scan_kernel(const int* __restrict__ bsum,
                                                        int* __restrict__ boff) {
    __shared__ int s[256];
    int t = threadIdx.x;
    int v = (t < NSB) ? bsum[t] : 0;
    s[t] = v;
    __syncthreads();
    for (int off = 1; off < 256; off <<= 1) {
        int cur = s[t];
        int add = (t >= off) ? s[t - off] : 0;
        __syncthreads();
        s[t] = cur + add;
        __syncthreads();
    }
    if (t < NSB) boff[t] = s[t] - v;
}

__global__ __launch_bounds__(256) void csr_setup_kernel(const int* __restrict__ deg,
                                                        const int* __restrict__ boff,
                                                        int* __restrict__ row_off,
                                                        float* __restrict__ dinv,
                                                        float* __restrict__ rdeg) {
    int b = blockIdx.x, t = threadIdx.x;
    int n = b * 256 + t;
    int v = (n < NN) ? deg[n] : 0;
    __shared__ int s[256];
    s[t] = v;
    __syncthreads();
    for (int off = 1; off < 256; off <<= 1) {
        int cur = s[t];
        int add = (t >= off) ? s[t - off] : 0;
        __syncthreads();
        s[t] = cur + add;
        __syncthreads();
    }
    int excl = s[t] - v + boff[b];
    if (n < NN) {
        row_off[n] = excl;
        float d = (float)v + 1.0f;
        dinv[n] = rsqrtf(d);
        rdeg[n] = sqrtf(d);
    }
    if (n == NN - 1) row_off[NN] = NE;
}

// partitioned, atomic-free scatter: only edges with dst in [d0,d1) write.
// dirty CSR region per pass ~0.8 MB -> L2-resident; nt reads don't evict it.
__global__ void scatter_pass_kernel(const int* __restrict__ src, const int* __restrict__ dst,
                                    const unsigned short* __restrict__ pos16,
                                    const int* __restrict__ row_off,
                                    int* __restrict__ csr_src, int d0, int d1) {
    int e = blockIdx.x * blockDim.x + threadIdx.x;
    if (e >= NE) return;
    int d = __builtin_nontemporal_load(&dst[e]);
    if (d < d0 || d >= d1) return;
    int s = __builtin_nontemporal_load(&src[e]);
    int p = (int)__builtin_nontemporal_load(&pos16[e]);
    csr_src[row_off[d] + p] = s;
}

// arow[n] = dinv[n] * (dinv[n] + sum_e dinv[src_e])
__global__ void arow_kernel(const int* __restrict__ row_off, const int* __restrict__ csr_src,
                            const float* __restrict__ dinv, float* __restrict__ arow) {
    int n = blockIdx.x * 256 + threadIdx.x;
    if (n >= NN) return;
    float dv = dinv[n];
    float s = dv;
    int e0 = row_off[n], e1 = row_off[n + 1];
    for (int i = e0; i < e1; ++i) s += dinv[csr_src[i]];
    arow[n] = dv * s;
}

// ---------------- CSR gather, channel-half blocked; optional fused BN stats ----------------
// hs is the dinv-prescaled table. sum = f(hs[r]) + sum_e f(hs[src_e]);  f = prelu if PRELU.
// OUT 0: dv*sum + bias   OUT 1: dv*(dv*sum + bias)   OUT 2: dv*sum
// STATS: accumulate sum/sumsq of rdeg[r]*f(hs[r]) (= prelu of true-scale h) into stats[128].

template <bool PRELU, int OUT, bool STATS>
__global__ __launch_bounds__(256) void gather_kernel(const int* __restrict__ row_off,
                                                     const int* __restrict__ csr_src,
                                                     const float* __restrict__ dinv,
                                                     const float* __restrict__ rdeg,
                                                     const float* __restrict__ bias,
                                                     const float* __restrict__ alpha_p,
                                                     const __half* __restrict__ hh,
                                                     __half* __restrict__ outp,
                                                     float* __restrict__ stats) {
    int tid = threadIdx.x;
    int r = blockIdx.x * 32 + (tid >> 3);
    int c = blockIdx.y * 32 + (tid & 7) * 4;
    bool valid = r < NN;
    if constexpr (!STATS) {
        if (!valid) return;
    }
    int rc = valid ? r : NN - 1;
    float alpha = 0.f;
    if constexpr (PRELU) alpha = alpha_p[0];
    uint2 u0 = *(const uint2*)&hh[(size_t)rc * 64 + c];
    float2 slo = up2(u0.x), shi = up2(u0.y);
    float s0 = slo.x, s1 = slo.y, s2 = shi.x, s3 = shi.y;
    if constexpr (PRELU) {
        s0 = s0 >= 0.f ? s0 : alpha * s0;
        s1 = s1 >= 0.f ? s1 : alpha * s1;
        s2 = s2 >= 0.f ? s2 : alpha * s2;
        s3 = s3 >= 0.f ? s3 : alpha * s3;
    }
    if constexpr (STATS) {
        __shared__ float st[256][8];
        float rd = valid ? rdeg[rc] : 0.f;
        float m0 = s0 * rd, m1 = s1 * rd, m2 = s2 * rd, m3 = s3 * rd;
        float* p = st[tid];
        p[0] = m0; p[1] = m1; p[2] = m2; p[3] = m3;
        p[4] = m0 * m0; p[5] = m1 * m1; p[6] = m2 * m2; p[7] = m3 * m3;
        __syncthreads();
        if (tid < 64) {
            int lane8 = tid & 7;
            int j = tid >> 3;
            float acc = 0.f;
            for (int row = 0; row < 32; ++row) acc += st[row * 8 + lane8][j];
            int ch = blockIdx.y * 32 + lane8 * 4 + (j & 3);
            atomicAdd(&stats[(j < 4 ? 0 : 64) + ch], acc);
        }
        if (!valid) return;
    }
    float ax = s0, ay = s1, az = s2, aw = s3;
    int beg = row_off[r];
    int end = row_off[r + 1];
    int i = beg;
    for (; i + 3 < end; i += 4) {
        int q0 = csr_src[i], q1 = csr_src[i + 1], q2 = csr_src[i + 2], q3 = csr_src[i + 3];
        uint2 v0 = *(const uint2*)&hh[(size_t)q0 * 64 + c];
        uint2 v1 = *(const uint2*)&hh[(size_t)q1 * 64 + c];
        uint2 v2 = *(const uint2*)&hh[(size_t)q2 * 64 + c];
        uint2 v3 = *(const uint2*)&hh[(size_t)q3 * 64 + c];
        float2 a0 = up2(v0.x), b0 = up2(v0.y);
        float2 a1 = up2(v1.x), b1 = up2(v1.y);
        float2 a2 = up2(v2.x), b2 = up2(v2.y);
        float2 a3 = up2(v3.x), b3 = up2(v3.y);
        if constexpr (PRELU) {
            a0.x = a0.x >= 0.f ? a0.x : alpha * a0.x;  a0.y = a0.y >= 0.f ? a0.y : alpha * a0.y;
            b0.x = b0.x >= 0.f ? b0.x : alpha * b0.x;  b0.y = b0.y >= 0.f ? b0.y : alpha * b0.y;
            a1.x = a1.x >= 0.f ? a1.x : alpha * a1.x;  a1.y = a1.y >= 0.f ? a1.y : alpha * a1.y;
            b1.x = b1.x >= 0.f ? b1.x : alpha * b1.x;  b1.y = b1.y >= 0.f ? b1.y : alpha * b1.y;
            a2.x = a2.x >= 0.f ? a2.x : alpha * a2.x;  a2.y = a2.y >= 0.f ? a2.y : alpha * a2.y;
            b2.x = b2.x >= 0.f ? b2.x : alpha * b2.x;  b2.y = b2.y >= 0.f ? b2.y : alpha * b2.y;
            a3.x = a3.x >= 0.f ? a3.x : alpha * a3.x;  a3.y = a3.y >= 0.f ? a3.y : alpha * a3.y;
            b3.x = b3.x >= 0.f ? b3.x : alpha * b3.x;  b3.y = b3.y >= 0.f ? b3.y : alpha * b3.y;
        }
        ax += (a0.x + a1.x) + (a2.x + a3.x);
        ay += (a0.y + a1.y) + (a2.y + a3.y);
        az += (b0.x + b1.x) + (b2.x + b3.x);
        aw += (b0.y + b1.y) + (b2.y + b3.y);
    }
    for (; i < end; ++i) {
        int q0 = csr_src[i];
        uint2 v0 = *(const uint2*)&hh[(size_t)q0 * 64 + c];
        float2 a0 = up2(v0.x), b0 = up2(v0.y);
        if constexpr (PRELU) {
            a0.x = a0.x >= 0.f ? a0.x : alpha * a0.x;  a0.y = a0.y >= 0.f ? a0.y : alpha * a0.y;
            b0.x = b0.x >= 0.f ? b0.x : alpha * b0.x;  b0.y = b0.y >= 0.f ? b0.y : alpha * b0.y;
        }
        ax += a0.x; ay += a0.y; az += b0.x; aw += b0.y;
    }
    float dv = dinv[r];
    float ox, oy, oz, ow;
    if constexpr (OUT == 2) {
        ox = dv * ax; oy = dv * ay; oz = dv * az; ow = dv * aw;
    } else {
        float4 b = *(const float4*)&bias[c];
        ox = dv * ax + b.x; oy = dv * ay + b.y; oz = dv * az + b.z; ow = dv * aw + b.w;
        if constexpr (OUT == 1) {
            ox *= dv; oy *= dv; oz *= dv; ow *= dv;
        }
    }
    uint2 o;
    o.x = pk2(ox, oy);
    o.y = pk2(oz, ow);
    *(uint2*)&outp[(size_t)r * 64 + c] = o;
}

// ---------------- pre-linear GEMM (f32 A): out16 = dinv * (x @ W + bias) ----------------

__global__ __launch_bounds__(256) void gemm_pre_kernel(const float* __restrict__ Af,
                                                       const float* __restrict__ W,
                                                       __half* __restrict__ outp,
                                                       const float* __restrict__ bias,
                                                       const float* __restrict__ dinv) {
    constexpr int K = 64, M = 64, BM = 128;
    constexpr int CG = M / 8;
    constexpr int RG = 256 / CG;
    constexpr int KP = K / 2;
    __shared__ unsigned Wh[KP * M];
    __shared__ unsigned Ahs[BM][KP + 4];
    int tid = threadIdx.x;
    for (int i = tid; i < KP * M; i += 256) {
        int kp = i / M, j = i % M;
        Wh[i] = pk2(W[(2 * kp) * M + j], W[(2 * kp + 1) * M + j]);
    }
    int r0 = blockIdx.x * BM;
    for (int i = tid; i < BM * (K / 4); i += 256) {
        int row = i / (K / 4);
        int k4 = (i % (K / 4)) * 4;
        int rr = r0 + row;
        if (rr > NN - 1) rr = NN - 1;
        float4 v = *(const float4*)&Af[(size_t)rr * K + k4];
        uint2 o;
        o.x = pk2(v.x, v.y);
        o.y = pk2(v.z, v.w);
        *(uint2*)&Ahs[row][k4 >> 1] = o;
    }
    __syncthreads();
    int cg = tid % CG, rg = tid / CG;
    int c = cg * 8;
    float acc[4][8];
#pragma unroll
    for (int r = 0; r < 4; ++r)
#pragma unroll
        for (int j = 0; j < 8; ++j) acc[r][j] = 0.f;
#pragma unroll 4
    for (int kp = 0; kp < KP; kp += 2) {
        uint2 a2[4];
#pragma unroll
        for (int r = 0; r < 4; ++r) a2[r] = *(const uint2*)&Ahs[rg + r * RG][kp];
#pragma unroll
        for (int kk = 0; kk < 2; ++kk) {
            const unsigned* wp = &Wh[(kp + kk) * M + c];
            uint4 w0 = *(const uint4*)wp;
            uint4 w1 = *(const uint4*)(wp + 4);
#pragma unroll
            for (int r = 0; r < 4; ++r) {
                unsigned av = kk ? a2[r].y : a2[r].x;
                acc[r][0] = fdot2u(av, w0.x, acc[r][0]);
                acc[r][1] = fdot2u(av, w0.y, acc[r][1]);
                acc[r][2] = fdot2u(av, w0.z, acc[r][2]);
                acc[r][3] = fdot2u(av, w0.w, acc[r][3]);
                acc[r][4] = fdot2u(av, w1.x, acc[r][4]);
                acc[r][5] = fdot2u(av, w1.y, acc[r][5]);
                acc[r][6] = fdot2u(av, w1.z, acc[r][6]);
                acc[r][7] = fdot2u(av, w1.w, acc[r][7]);
            }
        }
    }
    float4 b0 = *(const float4*)&bias[c];
    float4 b1 = *(const float4*)&bias[c + 4];
#pragma unroll
    for (int r = 0; r < 4; ++r) {
        int row = r0 + rg + r * RG;
        if (row < NN) {
            float sc = dinv[row];
            uint4 o;
            o.x = pk2((acc[r][0] + b0.x) * sc, (acc[r][1] + b0.y) * sc);
            o.y = pk2((acc[r][2] + b0.z) * sc, (acc[r][3] + b0.w) * sc);
            o.z = pk2((acc[r][4] + b1.x) * sc, (acc[r][5] + b1.y) * sc);
            o.w = pk2((acc[r][6] + b1.z) * sc, (acc[r][7] + b1.w) * sc);
            *(uint4*)&outp[(size_t)row * M + c] = o;
        }
    }
}

// ---------------- fused MFMA block MLP (in place on t16) ----------------
// t <- dinv * ( prelu( BN'(t) @ W1 + b1 ) @ W2 ), BM=64, 4 waves, U kept in LDS.
// A-frag: row=l&15, k=(l>>4)*8+j.  D: col=l&15, row=(l>>4)*4+reg.  [learn_hip m89/m97]

__global__ __launch_bounds__(256) void mfma_mlp_kernel(__half* __restrict__ t,
                                                       const float* __restrict__ W1,
                                                       const float* __restrict__ b1,
                                                       const float* __restrict__ W2,
                                                       const float* __restrict__ alpha2_p,
                                                       const float* __restrict__ stats,
                                                       const float* __restrict__ gamma,
                                                       const float* __restrict__ beta,
                                                       const float* __restrict__ arow,
                                                       const float* __restrict__ dinv) {
    __shared__ __align__(16) char smem[45056];
    auto Wt1 = (_Float16(*)[72])smem;             // [128][72]  (phase 2; 18432 B)
    auto Wt2 = (_Float16(*)[136])smem;            // [64][136]  aliases Wt1 (phase 3; 17408 B)
    auto At  = (_Float16(*)[72])(smem + 18432);   // [64][72]   (9216 B)
    auto Ut  = (_Float16(*)[136])(smem + 27648);  // [64][136]  (17408 B)
    __shared__ float scS[64], shS[64];
    int tid = threadIdx.x;
    if (tid < 64) {
        float mean = stats[tid] * (1.0f / NN);
        float var  = stats[64 + tid] * (1.0f / NN) - mean * mean;
        float sc = gamma[tid] * rsqrtf(var + BN_EPS);
        scS[tid] = sc;
        shS[tid] = beta[tid] - mean * sc;
    }
    for (int i = tid; i < 128 * 32; i += 256) {   // W1^T
        int j = i & 127;
        int k2 = i >> 7;
        *(unsigned*)&Wt1[j][2 * k2] = pk2(W1[(2 * k2) * 128 + j], W1[(2 * k2 + 1) * 128 + j]);
    }
    int r0 = blockIdx.x * 64;
    for (int i = tid; i < 64 * 16; i += 256) {    // A = BN'(t)
        int row = i >> 4;
        int k4 = (i & 15) * 4;
        int rr = r0 + row;
        if (rr > NN - 1) rr = NN - 1;
        uint2 uu = *(const uint2*)&t[(size_t)rr * 64 + k4];
        float2 lo = up2(uu.x), hi = up2(uu.y);
        float av = arow[rr];
        float vx = lo.x * scS[k4 + 0] + shS[k4 + 0] * av;
        float vy = lo.y * scS[k4 + 1] + shS[k4 + 1] * av;
        float vz = hi.x * scS[k4 + 2] + shS[k4 + 2] * av;
        float vw = hi.y * scS[k4 + 3] + shS[k4 + 3] * av;
        *(unsigned*)&At[row][k4]     = pk2(vx, vy);
        *(unsigned*)&At[row][k4 + 2] = pk2(vz, vw);
    }
    __syncthreads();
    int w = tid >> 6;
    int l = tid & 63;
    int lr = l & 15;
    int lk = (l >> 4) * 8;
    int rloc = w * 16 + (l >> 4) * 4;
    // phase 2: U = prelu(A @ W1 + b1)   (each wave: 16 rows x 128 cols)
    {
        f32x4 acc[8];
#pragma unroll
        for (int ct = 0; ct < 8; ++ct) acc[ct] = (f32x4){0.f, 0.f, 0.f, 0.f};
#pragma unroll
        for (int k0 = 0; k0 < 64; k0 += 32) {
            f16x8 a = *(const f16x8*)&At[w * 16 + lr][k0 + lk];
#pragma unroll
            for (int ct = 0; ct < 8; ++ct) {
                f16x8 b = *(const f16x8*)&Wt1[ct * 16 + lr][k0 + lk];
                acc[ct] = __builtin_amdgcn_mfma_f32_16x16x32_f16(a, b, acc[ct], 0, 0, 0);
            }
        }
        float alpha = alpha2_p[0];
#pragma unroll
        for (int ct = 0; ct < 8; ++ct) {
            int col = ct * 16 + lr;
            float bb = b1[col];
#pragma unroll
            for (int r = 0; r < 4; ++r) {
                float v = acc[ct][r] + bb;
                v = v >= 0.f ? v : alpha * v;
                Ut[rloc + r][col] = (_Float16)v;
            }
        }
    }
    __syncthreads();
    for (int i = tid; i < 64 * 64; i += 256) {    // W2^T into the Wt1 region
        int j = i & 63;
        int k2 = i >> 6;
        *(unsigned*)&Wt2[j][2 * k2] = pk2(W2[(2 * k2) * 64 + j], W2[(2 * k2 + 1) * 64 + j]);
    }
    __syncthreads();
    // phase 3: t = dinv * (U @ W2)   (each wave: 16 rows x 64 cols)
    {
        f32x4 acc[4];
#pragma unroll
        for (int ct = 0; ct < 4; ++ct) acc[ct] = (f32x4){0.f, 0.f, 0.f, 0.f};
#pragma unroll
        for (int k0 = 0; k0 < 128; k0 += 32) {
            f16x8 a = *(const f16x8*)&Ut[w * 16 + lr][k0 + lk];
#pragma unroll
            for (int ct = 0; ct < 4; ++ct) {
                f16x8 b = *(const f16x8*)&Wt2[ct * 16 + lr][k0 + lk];
                acc[ct] = __builtin_amdgcn_mfma_f32_16x16x32_f16(a, b, acc[ct], 0, 0, 0);
            }
        }
#pragma unroll
        for (int ct = 0; ct < 4; ++ct) {
            int col = ct * 16 + lr;
#pragma unroll
            for (int r = 0; r < 4; ++r) {
                int row = r0 + rloc + r;
                if (row < NN) t[(size_t)row * 64 + col] = __float2half(acc[ct][r] * dinv[row]);
            }
        }
    }
}

// ---------------- pool: one block per graph (batch sorted), fp16 in, f32 out ----------------

__global__ __launch_bounds__(256) void pool_seg_kernel(const __half* __restrict__ h,
                                                       const int* __restrict__ batch,
                                                       float* __restrict__ pooled) {
    int g = blockIdx.x;
    __shared__ int sbeg, send;
    int tid = threadIdx.x;
    if (tid == 0) {
        int lo = 0, hi = NN;
        while (lo < hi) { int mid = (lo + hi) >> 1; if (batch[mid] < g) lo = mid + 1; else hi = mid; }
        sbeg = lo;
        lo = 0; hi = NN;
        while (lo < hi) { int mid = (lo + hi) >> 1; if (batch[mid] < g + 1) lo = mid + 1; else hi = mid; }
        send = lo;
    }
    __syncthreads();
    int beg = sbeg, end = send;
    int c4 = (tid & 15) * 4;
    int rg = tid >> 4;
    float sx = 0, sy = 0, sz = 0, sw = 0;
    for (int n = beg + rg; n < end; n += 16) {
        uint2 u = *(const uint2*)&h[(size_t)n * 64 + c4];
        float2 lo = up2(u.x), hi = up2(u.y);
        sx += lo.x; sy += lo.y; sz += hi.x; sw += hi.y;
    }
    __shared__ float red[256 * 4];
    float* p = &red[tid * 4];
    p[0] = sx; p[1] = sy; p[2] = sz; p[3] = sw;
    __syncthreads();
    if (tid < 64) {
        int cg = tid >> 2;
        int j = tid & 3;
        float acc = 0.f;
        for (int r = 0; r < 16; ++r) acc += red[(r * 16 + cg) * 4 + j];
        float cnt = fmaxf((float)(end - beg), 1.0f);
        pooled[g * 64 + cg * 4 + j] = acc / cnt;
    }
}

// ---------------- head ----------------

__global__ __launch_bounds__(64) void head_stats_kernel(const float* __restrict__ pooled,
                                                        const float* __restrict__ gamma,
                                                        const float* __restrict__ beta,
                                                        float* __restrict__ headsc) {
    int ch = threadIdx.x;
    float s = 0.f, q = 0.f;
    for (int g = 0; g < 64; ++g) {
        float v = pooled[g * 64 + ch];
        s += v; q += v * v;
    }
    float mean = s * (1.0f / 64.0f);
    float var = q * (1.0f / 64.0f) - mean * mean;
    float sc = gamma[ch] * rsqrtf(var + BN_EPS);
    headsc[ch] = sc;
    headsc[64 + ch] = beta[ch] - mean * sc;
}

__global__ __launch_bounds__(256) void head_fc_kernel(const float* __restrict__ pooled,
                                                      const float* __restrict__ headsc,
                                                      const float* __restrict__ fc1w,
                                                      const float* __restrict__ fc1b,
                                                      const float* __restrict__ prelu_p,
                                                      const float* __restrict__ fc2w,
                                                      const float* __restrict__ fc2b,
                                                      float* __restrict__ out) {
    int g = blockIdx.x;
    int tid = threadIdx.x;
    __shared__ float pr[64];
    __shared__ float red[256];
    if (tid < 64) pr[tid] = pooled[g * 64 + tid] * headsc[tid] + headsc[64 + tid];
    __syncthreads();
    float alpha = prelu_p[0];
    float o1 = fc1b[tid];
    for (int k = 0; k < 64; ++k) o1 += pr[k] * fc1w[k * 256 + tid];
    o1 = o1 >= 0.f ? o1 : alpha * o1;
    for (int c = 0; c < NC; ++c) {
        red[tid] = o1 * fc2w[tid * NC + c];
        __syncthreads();
        for (int off = 128; off > 0; off >>= 1) {
            if (tid < off) red[tid] += red[tid + off];
            __syncthreads();
        }
        if (tid == 0) out[g * NC + c] = red[0] + fc2b[c];
        __syncthreads();
    }
}

// ---------------- launch ----------------

extern "C" void kernel_launch(void* const* d_in, const int* in_sizes, int n_in,
                              void* d_out, int out_size, void* d_ws, size_t ws_size,
                              hipStream_t stream) {
    const float* x       = (const float*)d_in[0];
    const int*   ei      = (const int*)d_in[1];
    const int*   batch   = (const int*)d_in[2];
    const float* pre_w   = (const float*)d_in[3];
    const float* pre_b   = (const float*)d_in[4];
    const float* bp1     = (const float*)d_in[5];
    const float* bng     = (const float*)d_in[6];
    const float* bnb     = (const float*)d_in[7];
    const float* bw1     = (const float*)d_in[8];
    const float* bb1     = (const float*)d_in[9];
    const float* bp2     = (const float*)d_in[10];
    const float* bw2     = (const float*)d_in[11];
    const float* bb2     = (const float*)d_in[12];
    const float* pgamma  = (const float*)d_in[13];
    const float* pbeta   = (const float*)d_in[14];
    const float* fc1w    = (const float*)d_in[15];
    const float* fc1b    = (const float*)d_in[16];
    const float* pprelu  = (const float*)d_in[17];
    const float* fc2w    = (const float*)d_in[18];
    const float* fc2b    = (const float*)d_in[19];

    const int* src = ei;
    const int* dst = ei + NE;

    __half* hA16 = (__half*)d_ws;                      // [NN,64] prescaled (hs)
    __half* t16  = hA16 + (size_t)NN * 64;             // [NN,64]
    float* dinv  = (float*)(t16 + (size_t)NN * 64);    // [NN]
    float* rdeg  = dinv + NN;                          // [NN]
    float* arow  = rdeg + NN;                          // [NN]
    float* stats = arow + NN;                          // [3*128] (zeroed)
    float* pooledg = stats + 3 * 128;                  // [64*64]
    float* headsc  = pooledg + 64 * 64;                // [128]
    int*   csr_src = (int*)(headsc + 128);             // [NE]
    int*   row_off = csr_src + NE;                     // [NN+1]
    int*   deg     = row_off + NN + 1;                 // [NN] (zeroed)
    int*   bsum    = deg + NN;                         // [NSB]
    int*   boff    = bsum + NSB;                       // [NSB]
    unsigned short* pos16 = (unsigned short*)(boff + NSB);   // [NE]

    hipMemsetAsync(stats, 0, (size_t)3 * 128 * 4, stream);
    hipMemsetAsync(deg, 0, (size_t)NN * 4, stream);

    deg_count_kernel<<<(NE + 255) / 256, 256, 0, stream>>>(dst, deg, pos16);
    block_sum_kernel<<<NSB, 256, 0, stream>>>(deg, bsum);
    bsum_scan_kernel<<<1, 256, 0, stream>>>(bsum, boff);
    csr_setup_kernel<<<NSB, 256, 0, stream>>>(deg, boff, row_off, dinv, rdeg);
    for (int p = 0; p < 4; ++p) {
        int d0 = p * 12500;
        int d1 = (p == 3) ? NN : d0 + 12500;
        scatter_pass_kernel<<<(NE + 255) / 256, 256, 0, stream>>>(
            src, dst, pos16, row_off, csr_src, d0, d1);
    }
    arow_kernel<<<(NN + 255) / 256, 256, 0, stream>>>(row_off, csr_src, dinv, arow);

    // pre-linear: hA16 = dinv * (x @ pre_w + pre_b)
    gemm_pre_kernel<<<(NN + 127) / 128, 256, 0, stream>>>(x, pre_w, hA16, pre_b, dinv);

    dim3 ggrid((NN + 31) / 32, 2);
    for (int i = 0; i < 3; ++i) {
        const float* a1 = bp1 + i;
        const float* a2 = bp2 + i;
        const float* gm = bng + i * 64;
        const float* bt = bnb + i * 64;
        const float* w1 = bw1 + (size_t)i * 64 * 128;
        const float* b1 = bb1 + i * 128;
        const float* w2 = bw2 + (size_t)i * 128 * 64;
        const float* b2 = bb2 + i * 64;
        float* st = stats + i * 128;

        // t16 = A_hat @ prelu(h) (true scale), fused BN-stats accumulation
        gather_kernel<true, 2, true><<<ggrid, 256, 0, stream>>>(
            row_off, csr_src, dinv, rdeg, nullptr, a1, hA16, t16, st);
        // t16 <- dinv * ( prelu( BN'(t16) @ w1 + b1 ) @ w2 )  (fused MFMA MLP, in place)
        mfma_mlp_kernel<<<(NN + 63) / 64, 256, 0, stream>>>(
            t16, w1, b1, w2, a2, st, gm, bt, arow, dinv);
        // hA16 = A_hat @ t16 + b2  (prescaled except last block)
        if (i < 2) {
            gather_kernel<false, 1, false><<<ggrid, 256, 0, stream>>>(
                row_off, csr_src, dinv, rdeg, b2, nullptr, t16, hA16, nullptr);
        } else {
            gather_kernel<false, 0, false><<<ggrid, 256, 0, stream>>>(
                row_off, csr_src, dinv, rdeg, b2, nullptr, t16, hA16, nullptr);
        }
    }

    pool_seg_kernel<<<NG, 256, 0, stream>>>(hA16, batch, pooledg);
    head_stats_kernel<<<1, 64, 0, stream>>>(pooledg, pgamma, pbeta, headsc);
    head_fc_kernel<<<NG, 256, 0, stream>>>(pooledg, headsc, fc1w, fc1b, pprelu,
                                           fc2w, fc2b, (float*)d_out);
}

// Round 11
// 385.095 us; speedup vs baseline: 1.1589x; 1.1589x over previous
//
#include <hip/hip_runtime.h>
#include <hip/hip_fp16.h>

#define NN 50000
#define NE 800000
#define NG 64
#define NC 10
#define BN_EPS 1e-5f
#define NSB 196   // ceil(NN/256)

typedef __attribute__((ext_vector_type(2))) _Float16 h2v;
typedef __attribute__((ext_vector_type(8))) _Float16 f16x8;
typedef __attribute__((ext_vector_type(4))) float f32x4;

__device__ __forceinline__ float2 up2(unsigned u) {
    __half2 h = *reinterpret_cast<__half2*>(&u);
    return __half22float2(h);
}
__device__ __forceinline__ unsigned pk2(float a, float b) {
    __half2 h = __floats2half2_rn(a, b);
    return *reinterpret_cast<unsigned*>(&h);
}
__device__ __forceinline__ float fdot2u(unsigned a, unsigned b, float c) {
    return __builtin_amdgcn_fdot2(__builtin_bit_cast(h2v, a), __builtin_bit_cast(h2v, b), c, false);
}

// ---------------- CSR build ----------------

__global__ void deg_count_kernel(const int* __restrict__ dst, int* __restrict__ deg,
                                 unsigned short* __restrict__ pos16) {
    int e = blockIdx.x * blockDim.x + threadIdx.x;
    if (e < NE) {
        int d = __builtin_nontemporal_load(&dst[e]);
        unsigned short p = (unsigned short)atomicAdd(&deg[d], 1);
        __builtin_nontemporal_store(p, &pos16[e]);
    }
}

__global__ __launch_bounds__(256) void block_sum_kernel(const int* __restrict__ deg,
                                                        int* __restrict__ bsum) {
    int b = blockIdx.x, t = threadIdx.x;
    int n = b * 256 + t;
    int v = (n < NN) ? deg[n] : 0;
    __shared__ int red[256];
    red[t] = v;
    __syncthreads();
    for (int off = 128; off > 0; off >>= 1) {
        if (t < off) red[t] += red[t + off];
        __syncthreads();
    }
    if (t == 0) bsum[b] = red[0];
}

__global__ __launch_bounds__(256) void bsum_scan_kernel(const int* __restrict__ bsum,
                                                        int* __restrict__ boff) {
    __shared__ int s[256];
    int t = threadIdx.x;
    int v = (t < NSB) ? bsum[t] : 0;
    s[t] = v;
    __syncthreads();
    for (int off = 1; off < 256; off <<= 1) {
        int cur = s[t];
        int add = (t >= off) ? s[t - off] : 0;
        __syncthreads();
        s[t] = cur + add;
        __syncthreads();
    }
    if (t < NSB) boff[t] = s[t] - v;
}

__global__ __launch_bounds__(256) void csr_setup_kernel(const int* __restrict__ deg,
                                                        const int* __restrict__ boff,
                                                        int* __restrict__ row_off,
                                                        float* __restrict__ dinv,
                                                        float* __restrict__ rdeg) {
    int b = blockIdx.x, t = threadIdx.x;
    int n = b * 256 + t;
    int v = (n < NN) ? deg[n] : 0;
    __shared__ int s[256];
    s[t] = v;
    __syncthreads();
    for (int off = 1; off < 256; off <<= 1) {
        int cur = s[t];
        int add = (t >= off) ? s[t - off] : 0;
        __syncthreads();
        s[t] = cur + add;
        __syncthreads();
    }
    int excl = s[t] - v + boff[b];
    if (n < NN) {
        row_off[n] = excl;
        float d = (float)v + 1.0f;
        dinv[n] = rsqrtf(d);
        rdeg[n] = sqrtf(d);
    }
    if (n == NN - 1) row_off[NN] = NE;
}

__global__ void scatter_csr_kernel(const int* __restrict__ src, const int* __restrict__ dst,
                                   const unsigned short* __restrict__ pos16,
                                   const int* __restrict__ row_off,
                                   int* __restrict__ csr_src) {
    int e = blockIdx.x * blockDim.x + threadIdx.x;
    if (e >= NE) return;
    int s = __builtin_nontemporal_load(&src[e]);
    int d = __builtin_nontemporal_load(&dst[e]);
    int p = (int)__builtin_nontemporal_load(&pos16[e]);
    csr_src[row_off[d] + p] = s;
}

// arow[n] = dinv[n] * (dinv[n] + sum_e dinv[src_e])
__global__ void arow_kernel(const int* __restrict__ row_off, const int* __restrict__ csr_src,
                            const float* __restrict__ dinv, float* __restrict__ arow) {
    int n = blockIdx.x * 256 + threadIdx.x;
    if (n >= NN) return;
    float dv = dinv[n];
    float s = dv;
    int e0 = row_off[n], e1 = row_off[n + 1];
    for (int i = e0; i < e1; ++i) s += dinv[csr_src[i]];
    arow[n] = dv * s;
}

// ---------------- BN stats over prelu(h_true) where h_true = rdeg * hs ----------------

__global__ __launch_bounds__(256) void bn_stats_kernel(const __half* __restrict__ h,
                                                       const float* __restrict__ rdeg,
                                                       const float* __restrict__ alpha_p,
                                                       float* __restrict__ stats) {
    float alpha = alpha_p[0];
    int tid = threadIdx.x;
    int c4 = (tid & 15) * 4;
    int rg = tid >> 4;
    float sx = 0, sy = 0, sz = 0, sw = 0;
    float qx = 0, qy = 0, qz = 0, qw = 0;
    for (int n = blockIdx.x * 16 + rg; n < NN; n += gridDim.x * 16) {
        float rd = rdeg[n];
        uint2 u = *(const uint2*)&h[(size_t)n * 64 + c4];
        float2 lo = up2(u.x), hi = up2(u.y);
        float a = lo.x >= 0.f ? lo.x : alpha * lo.x;
        float b = lo.y >= 0.f ? lo.y : alpha * lo.y;
        float c = hi.x >= 0.f ? hi.x : alpha * hi.x;
        float d = hi.y >= 0.f ? hi.y : alpha * hi.y;
        a *= rd; b *= rd; c *= rd; d *= rd;
        sx += a; sy += b; sz += c; sw += d;
        qx += a * a; qy += b * b; qz += c * c; qw += d * d;
    }
    __shared__ float ls[256 * 8];
    float* p = &ls[tid * 8];
    p[0] = sx; p[1] = sy; p[2] = sz; p[3] = sw;
    p[4] = qx; p[5] = qy; p[6] = qz; p[7] = qw;
    __syncthreads();
    if (tid < 128) {
        int cidx = tid >> 3;
        int j = tid & 7;
        float acc = 0.f;
        for (int r = 0; r < 16; ++r) acc += ls[(r * 16 + cidx) * 8 + j];
        int ch = cidx * 4 + (j & 3);
        if (j < 4) atomicAdd(&stats[ch], acc);
        else       atomicAdd(&stats[64 + ch], acc);
    }
}

// ---------------- CSR gather, channel-half blocked, software-pipelined 8-wide ----------------
// hs prescaled; sum = f(hs[r]) + sum_e f(hs[src_e]);  f = prelu if PRELU
// OUT 0: dv*sum + bias   OUT 1: dv*(dv*sum + bias)   OUT 2: dv*sum

template <bool PRELU, int OUT>
__global__ __launch_bounds__(256) void gather_kernel(const int* __restrict__ row_off,
                                                     const int* __restrict__ csr_src,
                                                     const float* __restrict__ dinv,
                                                     const float* __restrict__ bias,
                                                     const float* __restrict__ alpha_p,
                                                     const __half* __restrict__ hh,
                                                     __half* __restrict__ outp) {
    int tid = threadIdx.x;
    int r = blockIdx.x * 32 + (tid >> 3);
    int c = blockIdx.y * 32 + (tid & 7) * 4;
    if (r >= NN) return;
    float alpha = 0.f;
    if constexpr (PRELU) alpha = alpha_p[0];
    uint2 u0 = *(const uint2*)&hh[(size_t)r * 64 + c];
    float2 slo = up2(u0.x), shi = up2(u0.y);
    float ax = slo.x, ay = slo.y, az = shi.x, aw = shi.y;
    if constexpr (PRELU) {
        ax = ax >= 0.f ? ax : alpha * ax;
        ay = ay >= 0.f ? ay : alpha * ay;
        az = az >= 0.f ? az : alpha * az;
        aw = aw >= 0.f ? aw : alpha * aw;
    }
    int beg = row_off[r];
    int end = row_off[r + 1];
    int nct = (end - beg + 7) >> 3;     // uniform 8-edge chunks, clamped + masked
    int base = beg;
    int q[8];
    if (nct > 0) {
#pragma unroll
        for (int j = 0; j < 8; ++j) {
            int pos = base + j;
            q[j] = csr_src[pos < end ? pos : end - 1];
        }
    }
    for (int it = 0; it < nct; ++it) {
        int s[8];
#pragma unroll
        for (int j = 0; j < 8; ++j) s[j] = q[j];
        int cbase = base;
        base += 8;
        if (it + 1 < nct) {
            // prefetch next chunk's indices: latency overlaps the h-loads below
#pragma unroll
            for (int j = 0; j < 8; ++j) {
                int pos = base + j;
                q[j] = csr_src[pos < end ? pos : end - 1];
            }
        }
        uint2 v[8];
#pragma unroll
        for (int j = 0; j < 8; ++j) v[j] = *(const uint2*)&hh[(size_t)s[j] * 64 + c];
#pragma unroll
        for (int j = 0; j < 8; ++j) {
            float m = (cbase + j < end) ? 1.f : 0.f;
            float2 a = up2(v[j].x), b = up2(v[j].y);
            if constexpr (PRELU) {
                a.x = a.x >= 0.f ? a.x : alpha * a.x;
                a.y = a.y >= 0.f ? a.y : alpha * a.y;
                b.x = b.x >= 0.f ? b.x : alpha * b.x;
                b.y = b.y >= 0.f ? b.y : alpha * b.y;
            }
            ax = fmaf(a.x, m, ax);
            ay = fmaf(a.y, m, ay);
            az = fmaf(b.x, m, az);
            aw = fmaf(b.y, m, aw);
        }
    }
    float dv = dinv[r];
    float ox, oy, oz, ow;
    if constexpr (OUT == 2) {
        ox = dv * ax; oy = dv * ay; oz = dv * az; ow = dv * aw;
    } else {
        float4 b = *(const float4*)&bias[c];
        ox = dv * ax + b.x; oy = dv * ay + b.y; oz = dv * az + b.z; ow = dv * aw + b.w;
        if constexpr (OUT == 1) {
            ox *= dv; oy *= dv; oz *= dv; ow *= dv;
        }
    }
    uint2 o;
    o.x = pk2(ox, oy);
    o.y = pk2(oz, ow);
    *(uint2*)&outp[(size_t)r * 64 + c] = o;
}

// ---------------- pre-linear GEMM (f32 A): out16 = dinv * (x @ W + bias) ----------------

__global__ __launch_bounds__(256) void gemm_pre_kernel(const float* __restrict__ Af,
                                                       const float* __restrict__ W,
                                                       __half* __restrict__ outp,
                                                       const float* __restrict__ bias,
                                                       const float* __restrict__ dinv) {
    constexpr int K = 64, M = 64, BM = 128;
    constexpr int CG = M / 8;
    constexpr int RG = 256 / CG;
    constexpr int KP = K / 2;
    __shared__ unsigned Wh[KP * M];
    __shared__ unsigned Ahs[BM][KP + 4];
    int tid = threadIdx.x;
    for (int i = tid; i < KP * M; i += 256) {
        int kp = i / M, j = i % M;
        Wh[i] = pk2(W[(2 * kp) * M + j], W[(2 * kp + 1) * M + j]);
    }
    int r0 = blockIdx.x * BM;
    for (int i = tid; i < BM * (K / 4); i += 256) {
        int row = i / (K / 4);
        int k4 = (i % (K / 4)) * 4;
        int rr = r0 + row;
        if (rr > NN - 1) rr = NN - 1;
        float4 v = *(const float4*)&Af[(size_t)rr * K + k4];
        uint2 o;
        o.x = pk2(v.x, v.y);
        o.y = pk2(v.z, v.w);
        *(uint2*)&Ahs[row][k4 >> 1] = o;
    }
    __syncthreads();
    int cg = tid % CG, rg = tid / CG;
    int c = cg * 8;
    float acc[4][8];
#pragma unroll
    for (int r = 0; r < 4; ++r)
#pragma unroll
        for (int j = 0; j < 8; ++j) acc[r][j] = 0.f;
#pragma unroll 4
    for (int kp = 0; kp < KP; kp += 2) {
        uint2 a2[4];
#pragma unroll
        for (int r = 0; r < 4; ++r) a2[r] = *(const uint2*)&Ahs[rg + r * RG][kp];
#pragma unroll
        for (int kk = 0; kk < 2; ++kk) {
            const unsigned* wp = &Wh[(kp + kk) * M + c];
            uint4 w0 = *(const uint4*)wp;
            uint4 w1 = *(const uint4*)(wp + 4);
#pragma unroll
            for (int r = 0; r < 4; ++r) {
                unsigned av = kk ? a2[r].y : a2[r].x;
                acc[r][0] = fdot2u(av, w0.x, acc[r][0]);
                acc[r][1] = fdot2u(av, w0.y, acc[r][1]);
                acc[r][2] = fdot2u(av, w0.z, acc[r][2]);
                acc[r][3] = fdot2u(av, w0.w, acc[r][3]);
                acc[r][4] = fdot2u(av, w1.x, acc[r][4]);
                acc[r][5] = fdot2u(av, w1.y, acc[r][5]);
                acc[r][6] = fdot2u(av, w1.z, acc[r][6]);
                acc[r][7] = fdot2u(av, w1.w, acc[r][7]);
            }
        }
    }
    float4 b0 = *(const float4*)&bias[c];
    float4 b1 = *(const float4*)&bias[c + 4];
#pragma unroll
    for (int r = 0; r < 4; ++r) {
        int row = r0 + rg + r * RG;
        if (row < NN) {
            float sc = dinv[row];
            uint4 o;
            o.x = pk2((acc[r][0] + b0.x) * sc, (acc[r][1] + b0.y) * sc);
            o.y = pk2((acc[r][2] + b0.z) * sc, (acc[r][3] + b0.w) * sc);
            o.z = pk2((acc[r][4] + b1.x) * sc, (acc[r][5] + b1.y) * sc);
            o.w = pk2((acc[r][6] + b1.z) * sc, (acc[r][7] + b1.w) * sc);
            *(uint4*)&outp[(size_t)row * M + c] = o;
        }
    }
}

// ---------------- MFMA GEMM 1: u[N,128] = BN'(t[N,64]) @ W1 + b1 ----------------
// A-frag: row = l&15, k = (l>>4)*8 + j.  D: col = l&15, row = (l>>4)*4 + reg. [m89/m97]

__global__ __launch_bounds__(256) void mfma_gemm1_kernel(const __half* __restrict__ t,
                                                         const float* __restrict__ W1,
                                                         const float* __restrict__ b1,
                                                         __half* __restrict__ u,
                                                         const float* __restrict__ stats,
                                                         const float* __restrict__ gamma,
                                                         const float* __restrict__ beta,
                                                         const float* __restrict__ arow) {
    __shared__ _Float16 At[128][72];
    __shared__ _Float16 Wt[128][72];
    __shared__ float scS[64], shS[64];
    int tid = threadIdx.x;
    if (tid < 64) {
        float mean = stats[tid] * (1.0f / NN);
        float var  = stats[64 + tid] * (1.0f / NN) - mean * mean;
        float sc = gamma[tid] * rsqrtf(var + BN_EPS);
        scS[tid] = sc;
        shS[tid] = beta[tid] - mean * sc;
    }
    for (int i = tid; i < 128 * 32; i += 256) {
        int j = i & 127;
        int k2 = i >> 7;
        *(unsigned*)&Wt[j][2 * k2] = pk2(W1[(2 * k2) * 128 + j], W1[(2 * k2 + 1) * 128 + j]);
    }
    __syncthreads();
    int r0 = blockIdx.x * 128;
    for (int i = tid; i < 128 * 16; i += 256) {
        int row = i >> 4;
        int k4 = (i & 15) * 4;
        int rr = r0 + row;
        if (rr > NN - 1) rr = NN - 1;
        uint2 uu = *(const uint2*)&t[(size_t)rr * 64 + k4];
        float2 lo = up2(uu.x), hi = up2(uu.y);
        float av = arow[rr];
        float vx = lo.x * scS[k4 + 0] + shS[k4 + 0] * av;
        float vy = lo.y * scS[k4 + 1] + shS[k4 + 1] * av;
        float vz = hi.x * scS[k4 + 2] + shS[k4 + 2] * av;
        float vw = hi.y * scS[k4 + 3] + shS[k4 + 3] * av;
        *(unsigned*)&At[row][k4]     = pk2(vx, vy);
        *(unsigned*)&At[row][k4 + 2] = pk2(vz, vw);
    }
    __syncthreads();
    int w = tid >> 6;
    int l = tid & 63;
    int lr = l & 15;
    int lk = (l >> 4) * 8;
    f32x4 acc[2][8];
#pragma unroll
    for (int rt = 0; rt < 2; ++rt)
#pragma unroll
        for (int ct = 0; ct < 8; ++ct) acc[rt][ct] = (f32x4){0.f, 0.f, 0.f, 0.f};
#pragma unroll
    for (int k0 = 0; k0 < 64; k0 += 32) {
        f16x8 a0 = *(const f16x8*)&At[w * 32 + lr][k0 + lk];
        f16x8 a1 = *(const f16x8*)&At[w * 32 + 16 + lr][k0 + lk];
#pragma unroll
        for (int ct = 0; ct < 8; ++ct) {
            f16x8 b = *(const f16x8*)&Wt[ct * 16 + lr][k0 + lk];
            acc[0][ct] = __builtin_amdgcn_mfma_f32_16x16x32_f16(a0, b, acc[0][ct], 0, 0, 0);
            acc[1][ct] = __builtin_amdgcn_mfma_f32_16x16x32_f16(a1, b, acc[1][ct], 0, 0, 0);
        }
    }
    int rowbase = r0 + w * 32 + (l >> 4) * 4;
#pragma unroll
    for (int rt = 0; rt < 2; ++rt) {
#pragma unroll
        for (int ct = 0; ct < 8; ++ct) {
            int col = ct * 16 + lr;
            float bb = b1[col];
#pragma unroll
            for (int r = 0; r < 4; ++r) {
                int row = rowbase + rt * 16 + r;
                if (row < NN) u[(size_t)row * 128 + col] = __float2half(acc[rt][ct][r] + bb);
            }
        }
    }
}

// ---------------- MFMA GEMM 2: t[N,64] = dinv * (prelu(u[N,128]) @ W2) ----------------

__global__ __launch_bounds__(256) void mfma_gemm2_kernel(const __half* __restrict__ u,
                                                         const float* __restrict__ W2,
                                                         const float* __restrict__ alpha_p,
                                                         const float* __restrict__ dinv,
                                                         __half* __restrict__ t) {
    __shared__ _Float16 Ut[64][136];
    __shared__ _Float16 Wt[64][136];
    int tid = threadIdx.x;
    float alpha = alpha_p[0];
    for (int i = tid; i < 64 * 64; i += 256) {
        int j = i & 63;
        int k2 = i >> 6;
        *(unsigned*)&Wt[j][2 * k2] = pk2(W2[(2 * k2) * 64 + j], W2[(2 * k2 + 1) * 64 + j]);
    }
    int r0 = blockIdx.x * 64;
    for (int i = tid; i < 64 * 32; i += 256) {
        int row = i >> 5;
        int k4 = (i & 31) * 4;
        int rr = r0 + row;
        if (rr > NN - 1) rr = NN - 1;
        uint2 uu = *(const uint2*)&u[(size_t)rr * 128 + k4];
        float2 lo = up2(uu.x), hi = up2(uu.y);
        float vx = lo.x >= 0.f ? lo.x : alpha * lo.x;
        float vy = lo.y >= 0.f ? lo.y : alpha * lo.y;
        float vz = hi.x >= 0.f ? hi.x : alpha * hi.x;
        float vw = hi.y >= 0.f ? hi.y : alpha * hi.y;
        *(unsigned*)&Ut[row][k4]     = pk2(vx, vy);
        *(unsigned*)&Ut[row][k4 + 2] = pk2(vz, vw);
    }
    __syncthreads();
    int w = tid >> 6;
    int l = tid & 63;
    int lr = l & 15;
    int lk = (l >> 4) * 8;
    f32x4 acc[4];
#pragma unroll
    for (int ct = 0; ct < 4; ++ct) acc[ct] = (f32x4){0.f, 0.f, 0.f, 0.f};
#pragma unroll
    for (int k0 = 0; k0 < 128; k0 += 32) {
        f16x8 a = *(const f16x8*)&Ut[w * 16 + lr][k0 + lk];
#pragma unroll
        for (int ct = 0; ct < 4; ++ct) {
            f16x8 b = *(const f16x8*)&Wt[ct * 16 + lr][k0 + lk];
            acc[ct] = __builtin_amdgcn_mfma_f32_16x16x32_f16(a, b, acc[ct], 0, 0, 0);
        }
    }
    int rowbase = r0 + w * 16 + (l >> 4) * 4;
#pragma unroll
    for (int ct = 0; ct < 4; ++ct) {
        int col = ct * 16 + lr;
#pragma unroll
        for (int r = 0; r < 4; ++r) {
            int row = rowbase + r;
            if (row < NN) t[(size_t)row * 64 + col] = __float2half(acc[ct][r] * dinv[row]);
        }
    }
}

// ---------------- pool: one block per graph (batch sorted), fp16 in, f32 out ----------------

__global__ __launch_bounds__(256) void pool_seg_kernel(const __half* __restrict__ h,
                                                       const int* __restrict__ batch,
                                                       float* __restrict__ pooled) {
    int g = blockIdx.x;
    __shared__ int sbeg, send;
    int tid = threadIdx.x;
    if (tid == 0) {
        int lo = 0, hi = NN;
        while (lo < hi) { int mid = (lo + hi) >> 1; if (batch[mid] < g) lo = mid + 1; else hi = mid; }
        sbeg = lo;
        lo = 0; hi = NN;
        while (lo < hi) { int mid = (lo + hi) >> 1; if (batch[mid] < g + 1) lo = mid + 1; else hi = mid; }
        send = lo;
    }
    __syncthreads();
    int beg = sbeg, end = send;
    int c4 = (tid & 15) * 4;
    int rg = tid >> 4;
    float sx = 0, sy = 0, sz = 0, sw = 0;
    for (int n = beg + rg; n < end; n += 16) {
        uint2 u = *(const uint2*)&h[(size_t)n * 64 + c4];
        float2 lo = up2(u.x), hi = up2(u.y);
        sx += lo.x; sy += lo.y; sz += hi.x; sw += hi.y;
    }
    __shared__ float red[256 * 4];
    float* p = &red[tid * 4];
    p[0] = sx; p[1] = sy; p[2] = sz; p[3] = sw;
    __syncthreads();
    if (tid < 64) {
        int cg = tid >> 2;
        int j = tid & 3;
        float acc = 0.f;
        for (int r = 0; r < 16; ++r) acc += red[(r * 16 + cg) * 4 + j];
        float cnt = fmaxf((float)(end - beg), 1.0f);
        pooled[g * 64 + cg * 4 + j] = acc / cnt;
    }
}

// ---------------- head ----------------

__global__ __launch_bounds__(64) void head_stats_kernel(const float* __restrict__ pooled,
                                                        const float* __restrict__ gamma,
                                                        const float* __restrict__ beta,
                                                        float* __restrict__ headsc) {
    int ch = threadIdx.x;
    float s = 0.f, q = 0.f;
    for (int g = 0; g < 64; ++g) {
        float v = pooled[g * 64 + ch];
        s += v; q += v * v;
    }
    float mean = s * (1.0f / 64.0f);
    float var = q * (1.0f / 64.0f) - mean * mean;
    float sc = gamma[ch] * rsqrtf(var + BN_EPS);
    headsc[ch] = sc;
    headsc[64 + ch] = beta[ch] - mean * sc;
}

__global__ __launch_bounds__(256) void head_fc_kernel(const float* __restrict__ pooled,
                                                      const float* __restrict__ headsc,
                                                      const float* __restrict__ fc1w,
                                                      const float* __restrict__ fc1b,
                                                      const float* __restrict__ prelu_p,
                                                      const float* __restrict__ fc2w,
                                                      const float* __restrict__ fc2b,
                                                      float* __restrict__ out) {
    int g = blockIdx.x;
    int tid = threadIdx.x;
    __shared__ float pr[64];
    __shared__ float red[256];
    if (tid < 64) pr[tid] = pooled[g * 64 + tid] * headsc[tid] + headsc[64 + tid];
    __syncthreads();
    float alpha = prelu_p[0];
    float o1 = fc1b[tid];
    for (int k = 0; k < 64; ++k) o1 += pr[k] * fc1w[k * 256 + tid];
    o1 = o1 >= 0.f ? o1 : alpha * o1;
    for (int c = 0; c < NC; ++c) {
        red[tid] = o1 * fc2w[tid * NC + c];
        __syncthreads();
        for (int off = 128; off > 0; off >>= 1) {
            if (tid < off) red[tid] += red[tid + off];
            __syncthreads();
        }
        if (tid == 0) out[g * NC + c] = red[0] + fc2b[c];
        __syncthreads();
    }
}

// ---------------- launch ----------------

extern "C" void kernel_launch(void* const* d_in, const int* in_sizes, int n_in,
                              void* d_out, int out_size, void* d_ws, size_t ws_size,
                              hipStream_t stream) {
    const float* x       = (const float*)d_in[0];
    const int*   ei      = (const int*)d_in[1];
    const int*   batch   = (const int*)d_in[2];
    const float* pre_w   = (const float*)d_in[3];
    const float* pre_b   = (const float*)d_in[4];
    const float* bp1     = (const float*)d_in[5];
    const float* bng     = (const float*)d_in[6];
    const float* bnb     = (const float*)d_in[7];
    const float* bw1     = (const float*)d_in[8];
    const float* bb1     = (const float*)d_in[9];
    const float* bp2     = (const float*)d_in[10];
    const float* bw2     = (const float*)d_in[11];
    const float* bb2     = (const float*)d_in[12];
    const float* pgamma  = (const float*)d_in[13];
    const float* pbeta   = (const float*)d_in[14];
    const float* fc1w    = (const float*)d_in[15];
    const float* fc1b    = (const float*)d_in[16];
    const float* pprelu  = (const float*)d_in[17];
    const float* fc2w    = (const float*)d_in[18];
    const float* fc2b    = (const float*)d_in[19];

    const int* src = ei;
    const int* dst = ei + NE;

    __half* hA16 = (__half*)d_ws;                      // [NN,64] prescaled (hs)
    __half* t16  = hA16 + (size_t)NN * 64;             // [NN,64]
    __half* u16  = t16 + (size_t)NN * 64;              // [NN,128]
    float* dinv  = (float*)(u16 + (size_t)NN * 128);   // [NN]
    float* rdeg  = dinv + NN;                          // [NN]
    float* arow  = rdeg + NN;                          // [NN]
    float* stats = arow + NN;                          // [3*128] (zeroed)
    float* pooledg = stats + 3 * 128;                  // [64*64]
    float* headsc  = pooledg + 64 * 64;                // [128]
    int*   csr_src = (int*)(headsc + 128);             // [NE]
    int*   row_off = csr_src + NE;                     // [NN+1]
    int*   deg     = row_off + NN + 1;                 // [NN] (zeroed)
    int*   bsum    = deg + NN;                         // [NSB]
    int*   boff    = bsum + NSB;                       // [NSB]
    unsigned short* pos16 = (unsigned short*)(boff + NSB);   // [NE]

    hipMemsetAsync(stats, 0, (size_t)3 * 128 * 4, stream);
    hipMemsetAsync(deg, 0, (size_t)NN * 4, stream);

    deg_count_kernel<<<(NE + 255) / 256, 256, 0, stream>>>(dst, deg, pos16);
    block_sum_kernel<<<NSB, 256, 0, stream>>>(deg, bsum);
    bsum_scan_kernel<<<1, 256, 0, stream>>>(bsum, boff);
    csr_setup_kernel<<<NSB, 256, 0, stream>>>(deg, boff, row_off, dinv, rdeg);
    scatter_csr_kernel<<<(NE + 255) / 256, 256, 0, stream>>>(src, dst, pos16, row_off, csr_src);
    arow_kernel<<<(NN + 255) / 256, 256, 0, stream>>>(row_off, csr_src, dinv, arow);

    // pre-linear: hA16 = dinv * (x @ pre_w + pre_b)
    gemm_pre_kernel<<<(NN + 127) / 128, 256, 0, stream>>>(x, pre_w, hA16, pre_b, dinv);

    dim3 ggrid((NN + 31) / 32, 2);
    for (int i = 0; i < 3; ++i) {
        const float* a1 = bp1 + i;
        const float* a2 = bp2 + i;
        const float* gm = bng + i * 64;
        const float* bt = bnb + i * 64;
        const float* w1 = bw1 + (size_t)i * 64 * 128;
        const float* b1 = bb1 + i * 128;
        const float* w2 = bw2 + (size_t)i * 128 * 64;
        const float* b2 = bb2 + i * 64;
        float* st = stats + i * 128;

        bn_stats_kernel<<<256, 256, 0, stream>>>(hA16, rdeg, a1, st);
        // t16 = A_hat @ prelu(h)  (true scale)
        gather_kernel<true, 2><<<ggrid, 256, 0, stream>>>(
            row_off, csr_src, dinv, nullptr, a1, hA16, t16);
        // u16 = BN'(t16) @ w1 + b1   (MFMA)
        mfma_gemm1_kernel<<<(NN + 127) / 128, 256, 0, stream>>>(
            t16, w1, b1, u16, st, gm, bt, arow);
        // t16 = dinv * (prelu(u16) @ w2)   (MFMA)
        mfma_gemm2_kernel<<<(NN + 63) / 64, 256, 0, stream>>>(
            u16, w2, a2, dinv, t16);
        // hA16 = A_hat @ t16 + b2  (prescaled except last block)
        if (i < 2) {
            gather_kernel<false, 1><<<ggrid, 256, 0, stream>>>(
                row_off, csr_src, dinv, b2, nullptr, t16, hA16);
        } else {
            gather_kernel<false, 0><<<ggrid, 256, 0, stream>>>(
                row_off, csr_src, dinv, b2, nullptr, t16, hA16);
        }
    }

    pool_seg_kernel<<<NG, 256, 0, stream>>>(hA16, batch, pooledg);
    head_stats_kernel<<<1, 64, 0, stream>>>(pooledg, pgamma, pbeta, headsc);
    head_fc_kernel<<<NG, 256, 0, stream>>>(pooledg, headsc, fc1w, fc1b, pprelu,
                                           fc2w, fc2b, (float*)d_out);
}

// Round 12
// 368.802 us; speedup vs baseline: 1.2101x; 1.0442x over previous
//
#include <hip/hip_runtime.h>
#include <hip/hip_fp16.h>

#define NN 50000
#define NE 800000
#define NG 64
#define NC 10
#define BN_EPS 1e-5f
#define NSB 196   // ceil(NN/256)

typedef __attribute__((ext_vector_type(2))) _Float16 h2v;
typedef __attribute__((ext_vector_type(8))) _Float16 f16x8;
typedef __attribute__((ext_vector_type(4))) float f32x4;

__device__ __forceinline__ float2 up2(unsigned u) {
    __half2 h = *reinterpret_cast<__half2*>(&u);
    return __half22float2(h);
}
__device__ __forceinline__ unsigned pk2(float a, float b) {
    __half2 h = __floats2half2_rn(a, b);
    return *reinterpret_cast<unsigned*>(&h);
}
__device__ __forceinline__ float fdot2u(unsigned a, unsigned b, float c) {
    return __builtin_amdgcn_fdot2(__builtin_bit_cast(h2v, a), __builtin_bit_cast(h2v, b), c, false);
}

// ---------------- CSR build ----------------

__global__ void deg_count_kernel(const int* __restrict__ dst, int* __restrict__ deg,
                                 unsigned short* __restrict__ pos16) {
    int e = blockIdx.x * blockDim.x + threadIdx.x;
    if (e < NE) {
        int d = __builtin_nontemporal_load(&dst[e]);
        unsigned short p = (unsigned short)atomicAdd(&deg[d], 1);
        __builtin_nontemporal_store(p, &pos16[e]);
    }
}

__global__ __launch_bounds__(256) void block_sum_kernel(const int* __restrict__ deg,
                                                        int* __restrict__ bsum) {
    int b = blockIdx.x, t = threadIdx.x;
    int n = b * 256 + t;
    int v = (n < NN) ? deg[n] : 0;
    __shared__ int red[256];
    red[t] = v;
    __syncthreads();
    for (int off = 128; off > 0; off >>= 1) {
        if (t < off) red[t] += red[t + off];
        __syncthreads();
    }
    if (t == 0) bsum[b] = red[0];
}

__global__ __launch_bounds__(256) void bsum_scan_kernel(const int* __restrict__ bsum,
                                                        int* __restrict__ boff) {
    __shared__ int s[256];
    int t = threadIdx.x;
    int v = (t < NSB) ? bsum[t] : 0;
    s[t] = v;
    __syncthreads();
    for (int off = 1; off < 256; off <<= 1) {
        int cur = s[t];
        int add = (t >= off) ? s[t - off] : 0;
        __syncthreads();
        s[t] = cur + add;
        __syncthreads();
    }
    if (t < NSB) boff[t] = s[t] - v;
}

__global__ __launch_bounds__(256) void csr_setup_kernel(const int* __restrict__ deg,
                                                        const int* __restrict__ boff,
                                                        int* __restrict__ row_off,
                                                        float* __restrict__ dinv,
                                                        float* __restrict__ rdeg) {
    int b = blockIdx.x, t = threadIdx.x;
    int n = b * 256 + t;
    int v = (n < NN) ? deg[n] : 0;
    __shared__ int s[256];
    s[t] = v;
    __syncthreads();
    for (int off = 1; off < 256; off <<= 1) {
        int cur = s[t];
        int add = (t >= off) ? s[t - off] : 0;
        __syncthreads();
        s[t] = cur + add;
        __syncthreads();
    }
    int excl = s[t] - v + boff[b];
    if (n < NN) {
        row_off[n] = excl;
        float d = (float)v + 1.0f;
        dinv[n] = rsqrtf(d);
        rdeg[n] = sqrtf(d);
    }
    if (n == NN - 1) row_off[NN] = NE;
}

// partitioned, atomic-free scatter: only edges with dst in [d0,d1) write.
// dirty CSR region per pass ~0.8 MB -> L2-resident; nt reads don't evict it.
__global__ void scatter_pass_kernel(const int* __restrict__ src, const int* __restrict__ dst,
                                    const unsigned short* __restrict__ pos16,
                                    const int* __restrict__ row_off,
                                    int* __restrict__ csr_src, int d0, int d1) {
    int e = blockIdx.x * blockDim.x + threadIdx.x;
    if (e >= NE) return;
    int d = __builtin_nontemporal_load(&dst[e]);
    if (d < d0 || d >= d1) return;
    int s = __builtin_nontemporal_load(&src[e]);
    int p = (int)__builtin_nontemporal_load(&pos16[e]);
    csr_src[row_off[d] + p] = s;
}

// arow[n] = dinv[n] * (dinv[n] + sum_e dinv[src_e])
__global__ void arow_kernel(const int* __restrict__ row_off, const int* __restrict__ csr_src,
                            const float* __restrict__ dinv, float* __restrict__ arow) {
    int n = blockIdx.x * 256 + threadIdx.x;
    if (n >= NN) return;
    float dv = dinv[n];
    float s = dv;
    int e0 = row_off[n], e1 = row_off[n + 1];
    for (int i = e0; i < e1; ++i) s += dinv[csr_src[i]];
    arow[n] = dv * s;
}

// ---------------- BN stats over prelu(h_true) where h_true = rdeg * hs ----------------

__global__ __launch_bounds__(256) void bn_stats_kernel(const __half* __restrict__ h,
                                                       const float* __restrict__ rdeg,
                                                       const float* __restrict__ alpha_p,
                                                       float* __restrict__ stats) {
    float alpha = alpha_p[0];
    int tid = threadIdx.x;
    int c4 = (tid & 15) * 4;
    int rg = tid >> 4;
    float sx = 0, sy = 0, sz = 0, sw = 0;
    float qx = 0, qy = 0, qz = 0, qw = 0;
    for (int n = blockIdx.x * 16 + rg; n < NN; n += gridDim.x * 16) {
        float rd = rdeg[n];
        uint2 u = *(const uint2*)&h[(size_t)n * 64 + c4];
        float2 lo = up2(u.x), hi = up2(u.y);
        float a = lo.x >= 0.f ? lo.x : alpha * lo.x;
        float b = lo.y >= 0.f ? lo.y : alpha * lo.y;
        float c = hi.x >= 0.f ? hi.x : alpha * hi.x;
        float d = hi.y >= 0.f ? hi.y : alpha * hi.y;
        a *= rd; b *= rd; c *= rd; d *= rd;
        sx += a; sy += b; sz += c; sw += d;
        qx += a * a; qy += b * b; qz += c * c; qw += d * d;
    }
    __shared__ float ls[256 * 8];
    float* p = &ls[tid * 8];
    p[0] = sx; p[1] = sy; p[2] = sz; p[3] = sw;
    p[4] = qx; p[5] = qy; p[6] = qz; p[7] = qw;
    __syncthreads();
    if (tid < 128) {
        int cidx = tid >> 3;
        int j = tid & 7;
        float acc = 0.f;
        for (int r = 0; r < 16; ++r) acc += ls[(r * 16 + cidx) * 8 + j];
        int ch = cidx * 4 + (j & 3);
        if (j < 4) atomicAdd(&stats[ch], acc);
        else       atomicAdd(&stats[64 + ch], acc);
    }
}

// ---------------- CSR gather, channel-half blocked, software-pipelined 8-wide ----------------
// hs prescaled; sum = f(hs[r]) + sum_e f(hs[src_e]);  f = prelu if PRELU
// OUT 0: dv*sum + bias   OUT 1: dv*(dv*sum + bias)   OUT 2: dv*sum

template <bool PRELU, int OUT>
__global__ __launch_bounds__(256) void gather_kernel(const int* __restrict__ row_off,
                                                     const int* __restrict__ csr_src,
                                                     const float* __restrict__ dinv,
                                                     const float* __restrict__ bias,
                                                     const float* __restrict__ alpha_p,
                                                     const __half* __restrict__ hh,
                                                     __half* __restrict__ outp) {
    int tid = threadIdx.x;
    int r = blockIdx.x * 32 + (tid >> 3);
    int c = blockIdx.y * 32 + (tid & 7) * 4;
    if (r >= NN) return;
    float alpha = 0.f;
    if constexpr (PRELU) alpha = alpha_p[0];
    uint2 u0 = *(const uint2*)&hh[(size_t)r * 64 + c];
    float2 slo = up2(u0.x), shi = up2(u0.y);
    float ax = slo.x, ay = slo.y, az = shi.x, aw = shi.y;
    if constexpr (PRELU) {
        ax = ax >= 0.f ? ax : alpha * ax;
        ay = ay >= 0.f ? ay : alpha * ay;
        az = az >= 0.f ? az : alpha * az;
        aw = aw >= 0.f ? aw : alpha * aw;
    }
    int beg = row_off[r];
    int end = row_off[r + 1];
    int nct = (end - beg + 7) >> 3;     // uniform 8-edge chunks, clamped + masked
    int base = beg;
    int q[8];
    if (nct > 0) {
#pragma unroll
        for (int j = 0; j < 8; ++j) {
            int pos = base + j;
            q[j] = csr_src[pos < end ? pos : end - 1];
        }
    }
    for (int it = 0; it < nct; ++it) {
        int s[8];
#pragma unroll
        for (int j = 0; j < 8; ++j) s[j] = q[j];
        int cbase = base;
        base += 8;
        if (it + 1 < nct) {
#pragma unroll
            for (int j = 0; j < 8; ++j) {
                int pos = base + j;
                q[j] = csr_src[pos < end ? pos : end - 1];
            }
        }
        uint2 v[8];
#pragma unroll
        for (int j = 0; j < 8; ++j) v[j] = *(const uint2*)&hh[(size_t)s[j] * 64 + c];
#pragma unroll
        for (int j = 0; j < 8; ++j) {
            float m = (cbase + j < end) ? 1.f : 0.f;
            float2 a = up2(v[j].x), b = up2(v[j].y);
            if constexpr (PRELU) {
                a.x = a.x >= 0.f ? a.x : alpha * a.x;
                a.y = a.y >= 0.f ? a.y : alpha * a.y;
                b.x = b.x >= 0.f ? b.x : alpha * b.x;
                b.y = b.y >= 0.f ? b.y : alpha * b.y;
            }
            ax = fmaf(a.x, m, ax);
            ay = fmaf(a.y, m, ay);
            az = fmaf(b.x, m, az);
            aw = fmaf(b.y, m, aw);
        }
    }
    float dv = dinv[r];
    float ox, oy, oz, ow;
    if constexpr (OUT == 2) {
        ox = dv * ax; oy = dv * ay; oz = dv * az; ow = dv * aw;
    } else {
        float4 b = *(const float4*)&bias[c];
        ox = dv * ax + b.x; oy = dv * ay + b.y; oz = dv * az + b.z; ow = dv * aw + b.w;
        if constexpr (OUT == 1) {
            ox *= dv; oy *= dv; oz *= dv; ow *= dv;
        }
    }
    uint2 o;
    o.x = pk2(ox, oy);
    o.y = pk2(oz, ow);
    *(uint2*)&outp[(size_t)r * 64 + c] = o;
}

// ---------------- pre-linear GEMM (f32 A): out16 = dinv * (x @ W + bias) ----------------

__global__ __launch_bounds__(256) void gemm_pre_kernel(const float* __restrict__ Af,
                                                       const float* __restrict__ W,
                                                       __half* __restrict__ outp,
                                                       const float* __restrict__ bias,
                                                       const float* __restrict__ dinv) {
    constexpr int K = 64, M = 64, BM = 128;
    constexpr int CG = M / 8;
    constexpr int RG = 256 / CG;
    constexpr int KP = K / 2;
    __shared__ unsigned Wh[KP * M];
    __shared__ unsigned Ahs[BM][KP + 4];
    int tid = threadIdx.x;
    for (int i = tid; i < KP * M; i += 256) {
        int kp = i / M, j = i % M;
        Wh[i] = pk2(W[(2 * kp) * M + j], W[(2 * kp + 1) * M + j]);
    }
    int r0 = blockIdx.x * BM;
    for (int i = tid; i < BM * (K / 4); i += 256) {
        int row = i / (K / 4);
        int k4 = (i % (K / 4)) * 4;
        int rr = r0 + row;
        if (rr > NN - 1) rr = NN - 1;
        float4 v = *(const float4*)&Af[(size_t)rr * K + k4];
        uint2 o;
        o.x = pk2(v.x, v.y);
        o.y = pk2(v.z, v.w);
        *(uint2*)&Ahs[row][k4 >> 1] = o;
    }
    __syncthreads();
    int cg = tid % CG, rg = tid / CG;
    int c = cg * 8;
    float acc[4][8];
#pragma unroll
    for (int r = 0; r < 4; ++r)
#pragma unroll
        for (int j = 0; j < 8; ++j) acc[r][j] = 0.f;
#pragma unroll 4
    for (int kp = 0; kp < KP; kp += 2) {
        uint2 a2[4];
#pragma unroll
        for (int r = 0; r < 4; ++r) a2[r] = *(const uint2*)&Ahs[rg + r * RG][kp];
#pragma unroll
        for (int kk = 0; kk < 2; ++kk) {
            const unsigned* wp = &Wh[(kp + kk) * M + c];
            uint4 w0 = *(const uint4*)wp;
            uint4 w1 = *(const uint4*)(wp + 4);
#pragma unroll
            for (int r = 0; r < 4; ++r) {
                unsigned av = kk ? a2[r].y : a2[r].x;
                acc[r][0] = fdot2u(av, w0.x, acc[r][0]);
                acc[r][1] = fdot2u(av, w0.y, acc[r][1]);
                acc[r][2] = fdot2u(av, w0.z, acc[r][2]);
                acc[r][3] = fdot2u(av, w0.w, acc[r][3]);
                acc[r][4] = fdot2u(av, w1.x, acc[r][4]);
                acc[r][5] = fdot2u(av, w1.y, acc[r][5]);
                acc[r][6] = fdot2u(av, w1.z, acc[r][6]);
                acc[r][7] = fdot2u(av, w1.w, acc[r][7]);
            }
        }
    }
    float4 b0 = *(const float4*)&bias[c];
    float4 b1 = *(const float4*)&bias[c + 4];
#pragma unroll
    for (int r = 0; r < 4; ++r) {
        int row = r0 + rg + r * RG;
        if (row < NN) {
            float sc = dinv[row];
            uint4 o;
            o.x = pk2((acc[r][0] + b0.x) * sc, (acc[r][1] + b0.y) * sc);
            o.y = pk2((acc[r][2] + b0.z) * sc, (acc[r][3] + b0.w) * sc);
            o.z = pk2((acc[r][4] + b1.x) * sc, (acc[r][5] + b1.y) * sc);
            o.w = pk2((acc[r][6] + b1.z) * sc, (acc[r][7] + b1.w) * sc);
            *(uint4*)&outp[(size_t)row * M + c] = o;
        }
    }
}

// ---------------- fused MFMA block MLP (in place on t16) ----------------
// t <- dinv * ( prelu( BN'(t) @ W1 + b1 ) @ W2 ), BM=64, 4 waves, U kept in LDS.
// A-frag: row=l&15, k=(l>>4)*8+j.  D: col=l&15, row=(l>>4)*4+reg.  [learn_hip m89/m97]

__global__ __launch_bounds__(256) void mfma_mlp_kernel(__half* __restrict__ t,
                                                       const float* __restrict__ W1,
                                                       const float* __restrict__ b1,
                                                       const float* __restrict__ W2,
                                                       const float* __restrict__ alpha2_p,
                                                       const float* __restrict__ stats,
                                                       const float* __restrict__ gamma,
                                                       const float* __restrict__ beta,
                                                       const float* __restrict__ arow,
                                                       const float* __restrict__ dinv) {
    __shared__ __align__(16) char smem[45056];
    auto Wt1 = (_Float16(*)[72])smem;             // [128][72]  (phase 2; 18432 B)
    auto Wt2 = (_Float16(*)[136])smem;            // [64][136]  aliases Wt1 (phase 3; 17408 B)
    auto At  = (_Float16(*)[72])(smem + 18432);   // [64][72]   (9216 B)
    auto Ut  = (_Float16(*)[136])(smem + 27648);  // [64][136]  (17408 B)
    __shared__ float scS[64], shS[64];
    int tid = threadIdx.x;
    if (tid < 64) {
        float mean = stats[tid] * (1.0f / NN);
        float var  = stats[64 + tid] * (1.0f / NN) - mean * mean;
        float sc = gamma[tid] * rsqrtf(var + BN_EPS);
        scS[tid] = sc;
        shS[tid] = beta[tid] - mean * sc;
    }
    for (int i = tid; i < 128 * 32; i += 256) {   // W1^T
        int j = i & 127;
        int k2 = i >> 7;
        *(unsigned*)&Wt1[j][2 * k2] = pk2(W1[(2 * k2) * 128 + j], W1[(2 * k2 + 1) * 128 + j]);
    }
    int r0 = blockIdx.x * 64;
    for (int i = tid; i < 64 * 16; i += 256) {    // A = BN'(t)
        int row = i >> 4;
        int k4 = (i & 15) * 4;
        int rr = r0 + row;
        if (rr > NN - 1) rr = NN - 1;
        uint2 uu = *(const uint2*)&t[(size_t)rr * 64 + k4];
        float2 lo = up2(uu.x), hi = up2(uu.y);
        float av = arow[rr];
        float vx = lo.x * scS[k4 + 0] + shS[k4 + 0] * av;
        float vy = lo.y * scS[k4 + 1] + shS[k4 + 1] * av;
        float vz = hi.x * scS[k4 + 2] + shS[k4 + 2] * av;
        float vw = hi.y * scS[k4 + 3] + shS[k4 + 3] * av;
        *(unsigned*)&At[row][k4]     = pk2(vx, vy);
        *(unsigned*)&At[row][k4 + 2] = pk2(vz, vw);
    }
    __syncthreads();
    int w = tid >> 6;
    int l = tid & 63;
    int lr = l & 15;
    int lk = (l >> 4) * 8;
    int rloc = w * 16 + (l >> 4) * 4;
    // phase 2: U = prelu(A @ W1 + b1)   (each wave: 16 rows x 128 cols)
    {
        f32x4 acc[8];
#pragma unroll
        for (int ct = 0; ct < 8; ++ct) acc[ct] = (f32x4){0.f, 0.f, 0.f, 0.f};
#pragma unroll
        for (int k0 = 0; k0 < 64; k0 += 32) {
            f16x8 a = *(const f16x8*)&At[w * 16 + lr][k0 + lk];
#pragma unroll
            for (int ct = 0; ct < 8; ++ct) {
                f16x8 b = *(const f16x8*)&Wt1[ct * 16 + lr][k0 + lk];
                acc[ct] = __builtin_amdgcn_mfma_f32_16x16x32_f16(a, b, acc[ct], 0, 0, 0);
            }
        }
        float alpha = alpha2_p[0];
#pragma unroll
        for (int ct = 0; ct < 8; ++ct) {
            int col = ct * 16 + lr;
            float bb = b1[col];
#pragma unroll
            for (int r = 0; r < 4; ++r) {
                float v = acc[ct][r] + bb;
                v = v >= 0.f ? v : alpha * v;
                Ut[rloc + r][col] = (_Float16)v;
            }
        }
    }
    __syncthreads();
    for (int i = tid; i < 64 * 64; i += 256) {    // W2^T into the Wt1 region
        int j = i & 63;
        int k2 = i >> 6;
        *(unsigned*)&Wt2[j][2 * k2] = pk2(W2[(2 * k2) * 64 + j], W2[(2 * k2 + 1) * 64 + j]);
    }
    __syncthreads();
    // phase 3: t = dinv * (U @ W2)   (each wave: 16 rows x 64 cols)
    {
        f32x4 acc[4];
#pragma unroll
        for (int ct = 0; ct < 4; ++ct) acc[ct] = (f32x4){0.f, 0.f, 0.f, 0.f};
#pragma unroll
        for (int k0 = 0; k0 < 128; k0 += 32) {
            f16x8 a = *(const f16x8*)&Ut[w * 16 + lr][k0 + lk];
#pragma unroll
            for (int ct = 0; ct < 4; ++ct) {
                f16x8 b = *(const f16x8*)&Wt2[ct * 16 + lr][k0 + lk];
                acc[ct] = __builtin_amdgcn_mfma_f32_16x16x32_f16(a, b, acc[ct], 0, 0, 0);
            }
        }
#pragma unroll
        for (int ct = 0; ct < 4; ++ct) {
            int col = ct * 16 + lr;
#pragma unroll
            for (int r = 0; r < 4; ++r) {
                int row = r0 + rloc + r;
                if (row < NN) t[(size_t)row * 64 + col] = __float2half(acc[ct][r] * dinv[row]);
            }
        }
    }
}

// ---------------- pool: one block per graph (batch sorted), fp16 in, f32 out ----------------

__global__ __launch_bounds__(256) void pool_seg_kernel(const __half* __restrict__ h,
                                                       const int* __restrict__ batch,
                                                       float* __restrict__ pooled) {
    int g = blockIdx.x;
    __shared__ int sbeg, send;
    int tid = threadIdx.x;
    if (tid == 0) {
        int lo = 0, hi = NN;
        while (lo < hi) { int mid = (lo + hi) >> 1; if (batch[mid] < g) lo = mid + 1; else hi = mid; }
        sbeg = lo;
        lo = 0; hi = NN;
        while (lo < hi) { int mid = (lo + hi) >> 1; if (batch[mid] < g + 1) lo = mid + 1; else hi = mid; }
        send = lo;
    }
    __syncthreads();
    int beg = sbeg, end = send;
    int c4 = (tid & 15) * 4;
    int rg = tid >> 4;
    float sx = 0, sy = 0, sz = 0, sw = 0;
    for (int n = beg + rg; n < end; n += 16) {
        uint2 u = *(const uint2*)&h[(size_t)n * 64 + c4];
        float2 lo = up2(u.x), hi = up2(u.y);
        sx += lo.x; sy += lo.y; sz += hi.x; sw += hi.y;
    }
    __shared__ float red[256 * 4];
    float* p = &red[tid * 4];
    p[0] = sx; p[1] = sy; p[2] = sz; p[3] = sw;
    __syncthreads();
    if (tid < 64) {
        int cg = tid >> 2;
        int j = tid & 3;
        float acc = 0.f;
        for (int r = 0; r < 16; ++r) acc += red[(r * 16 + cg) * 4 + j];
        float cnt = fmaxf((float)(end - beg), 1.0f);
        pooled[g * 64 + cg * 4 + j] = acc / cnt;
    }
}

// ---------------- head ----------------

__global__ __launch_bounds__(64) void head_stats_kernel(const float* __restrict__ pooled,
                                                        const float* __restrict__ gamma,
                                                        const float* __restrict__ beta,
                                                        float* __restrict__ headsc) {
    int ch = threadIdx.x;
    float s = 0.f, q = 0.f;
    for (int g = 0; g < 64; ++g) {
        float v = pooled[g * 64 + ch];
        s += v; q += v * v;
    }
    float mean = s * (1.0f / 64.0f);
    float var = q * (1.0f / 64.0f) - mean * mean;
    float sc = gamma[ch] * rsqrtf(var + BN_EPS);
    headsc[ch] = sc;
    headsc[64 + ch] = beta[ch] - mean * sc;
}

__global__ __launch_bounds__(256) void head_fc_kernel(const float* __restrict__ pooled,
                                                      const float* __restrict__ headsc,
                                                      const float* __restrict__ fc1w,
                                                      const float* __restrict__ fc1b,
                                                      const float* __restrict__ prelu_p,
                                                      const float* __restrict__ fc2w,
                                                      const float* __restrict__ fc2b,
                                                      float* __restrict__ out) {
    int g = blockIdx.x;
    int tid = threadIdx.x;
    __shared__ float pr[64];
    __shared__ float red[256];
    if (tid < 64) pr[tid] = pooled[g * 64 + tid] * headsc[tid] + headsc[64 + tid];
    __syncthreads();
    float alpha = prelu_p[0];
    float o1 = fc1b[tid];
    for (int k = 0; k < 64; ++k) o1 += pr[k] * fc1w[k * 256 + tid];
    o1 = o1 >= 0.f ? o1 : alpha * o1;
    for (int c = 0; c < NC; ++c) {
        red[tid] = o1 * fc2w[tid * NC + c];
        __syncthreads();
        for (int off = 128; off > 0; off >>= 1) {
            if (tid < off) red[tid] += red[tid + off];
            __syncthreads();
        }
        if (tid == 0) out[g * NC + c] = red[0] + fc2b[c];
        __syncthreads();
    }
}

// ---------------- launch ----------------

extern "C" void kernel_launch(void* const* d_in, const int* in_sizes, int n_in,
                              void* d_out, int out_size, void* d_ws, size_t ws_size,
                              hipStream_t stream) {
    const float* x       = (const float*)d_in[0];
    const int*   ei      = (const int*)d_in[1];
    const int*   batch   = (const int*)d_in[2];
    const float* pre_w   = (const float*)d_in[3];
    const float* pre_b   = (const float*)d_in[4];
    const float* bp1     = (const float*)d_in[5];
    const float* bng     = (const float*)d_in[6];
    const float* bnb     = (const float*)d_in[7];
    const float* bw1     = (const float*)d_in[8];
    const float* bb1     = (const float*)d_in[9];
    const float* bp2     = (const float*)d_in[10];
    const float* bw2     = (const float*)d_in[11];
    const float* bb2     = (const float*)d_in[12];
    const float* pgamma  = (const float*)d_in[13];
    const float* pbeta   = (const float*)d_in[14];
    const float* fc1w    = (const float*)d_in[15];
    const float* fc1b    = (const float*)d_in[16];
    const float* pprelu  = (const float*)d_in[17];
    const float* fc2w    = (const float*)d_in[18];
    const float* fc2b    = (const float*)d_in[19];

    const int* src = ei;
    const int* dst = ei + NE;

    __half* hA16 = (__half*)d_ws;                      // [NN,64] prescaled (hs)
    __half* t16  = hA16 + (size_t)NN * 64;             // [NN,64]
    float* dinv  = (float*)(t16 + (size_t)NN * 64);    // [NN]
    float* rdeg  = dinv + NN;                          // [NN]
    float* arow  = rdeg + NN;                          // [NN]
    float* stats = arow + NN;                          // [3*128] (zeroed)
    int*   deg   = (int*)(stats + 3 * 128);            // [NN]    (zeroed, adjacent to stats)
    float* pooledg = (float*)(deg + NN);               // [64*64]
    float* headsc  = pooledg + 64 * 64;                // [128]
    int*   csr_src = (int*)(headsc + 128);             // [NE]
    int*   row_off = csr_src + NE;                     // [NN+1]
    int*   bsum    = row_off + NN + 1;                 // [NSB]
    int*   boff    = bsum + NSB;                       // [NSB]
    unsigned short* pos16 = (unsigned short*)(boff + NSB);   // [NE]

    hipMemsetAsync(stats, 0, ((size_t)3 * 128 + NN) * 4, stream);

    deg_count_kernel<<<(NE + 255) / 256, 256, 0, stream>>>(dst, deg, pos16);
    block_sum_kernel<<<NSB, 256, 0, stream>>>(deg, bsum);
    bsum_scan_kernel<<<1, 256, 0, stream>>>(bsum, boff);
    csr_setup_kernel<<<NSB, 256, 0, stream>>>(deg, boff, row_off, dinv, rdeg);
    for (int p = 0; p < 4; ++p) {
        int d0 = p * 12500;
        int d1 = (p == 3) ? NN : d0 + 12500;
        scatter_pass_kernel<<<(NE + 255) / 256, 256, 0, stream>>>(
            src, dst, pos16, row_off, csr_src, d0, d1);
    }
    arow_kernel<<<(NN + 255) / 256, 256, 0, stream>>>(row_off, csr_src, dinv, arow);

    // pre-linear: hA16 = dinv * (x @ pre_w + pre_b)
    gemm_pre_kernel<<<(NN + 127) / 128, 256, 0, stream>>>(x, pre_w, hA16, pre_b, dinv);

    dim3 ggrid((NN + 31) / 32, 2);
    for (int i = 0; i < 3; ++i) {
        const float* a1 = bp1 + i;
        const float* a2 = bp2 + i;
        const float* gm = bng + i * 64;
        const float* bt = bnb + i * 64;
        const float* w1 = bw1 + (size_t)i * 64 * 128;
        const float* b1 = bb1 + i * 128;
        const float* w2 = bw2 + (size_t)i * 128 * 64;
        const float* b2 = bb2 + i * 64;
        float* st = stats + i * 128;

        bn_stats_kernel<<<256, 256, 0, stream>>>(hA16, rdeg, a1, st);
        // t16 = A_hat @ prelu(h)  (true scale)
        gather_kernel<true, 2><<<ggrid, 256, 0, stream>>>(
            row_off, csr_src, dinv, nullptr, a1, hA16, t16);
        // t16 <- dinv * ( prelu( BN'(t16) @ w1 + b1 ) @ w2 )  (fused MFMA MLP, in place)
        mfma_mlp_kernel<<<(NN + 63) / 64, 256, 0, stream>>>(
            t16, w1, b1, w2, a2, st, gm, bt, arow, dinv);
        // hA16 = A_hat @ t16 + b2  (prescaled except last block)
        if (i < 2) {
            gather_kernel<false, 1><<<ggrid, 256, 0, stream>>>(
                row_off, csr_src, dinv, b2, nullptr, t16, hA16);
        } else {
            gather_kernel<false, 0><<<ggrid, 256, 0, stream>>>(
                row_off, csr_src, dinv, b2, nullptr, t16, hA16);
        }
    }

    pool_seg_kernel<<<NG, 256, 0, stream>>>(hA16, batch, pooledg);
    head_stats_kernel<<<1, 64, 0, stream>>>(pooledg, pgamma, pbeta, headsc);
    head_fc_kernel<<<NG, 256, 0, stream>>>(pooledg, headsc, fc1w, fc1b, pprelu,
                                           fc2w, fc2b, (float*)d_out);
}

// Round 13
// 337.162 us; speedup vs baseline: 1.3237x; 1.0938x over previous
//
#include <hip/hip_runtime.h>
#include <hip/hip_fp16.h>

#define NN 50000
#define NE 800000
#define NG 64
#define NC 10
#define BN_EPS 1e-5f
#define NSB 196   // ceil(NN/256)

typedef __attribute__((ext_vector_type(2))) _Float16 h2v;
typedef __attribute__((ext_vector_type(8))) _Float16 f16x8;
typedef __attribute__((ext_vector_type(4))) float f32x4;

__device__ __forceinline__ float2 up2(unsigned u) {
    __half2 h = *reinterpret_cast<__half2*>(&u);
    return __half22float2(h);
}
__device__ __forceinline__ unsigned pk2(float a, float b) {
    __half2 h = __floats2half2_rn(a, b);
    return *reinterpret_cast<unsigned*>(&h);
}
__device__ __forceinline__ float fdot2u(unsigned a, unsigned b, float c) {
    return __builtin_amdgcn_fdot2(__builtin_bit_cast(h2v, a), __builtin_bit_cast(h2v, b), c, false);
}

// ---------------- CSR build ----------------

__global__ void deg_count_kernel(const int* __restrict__ dst, int* __restrict__ deg,
                                 unsigned short* __restrict__ pos16) {
    int e = blockIdx.x * blockDim.x + threadIdx.x;
    if (e < NE) {
        int d = __builtin_nontemporal_load(&dst[e]);
        unsigned short p = (unsigned short)atomicAdd(&deg[d], 1);
        __builtin_nontemporal_store(p, &pos16[e]);
    }
}

__global__ __launch_bounds__(256) void block_sum_kernel(const int* __restrict__ deg,
                                                        int* __restrict__ bsum) {
    int b = blockIdx.x, t = threadIdx.x;
    int n = b * 256 + t;
    int v = (n < NN) ? deg[n] : 0;
    __shared__ int red[256];
    red[t] = v;
    __syncthreads();
    for (int off = 128; off > 0; off >>= 1) {
        if (t < off) red[t] += red[t + off];
        __syncthreads();
    }
    if (t == 0) bsum[b] = red[0];
}

__global__ __launch_bounds__(256) void bsum_scan_kernel(const int* __restrict__ bsum,
                                                        int* __restrict__ boff) {
    __shared__ int s[256];
    int t = threadIdx.x;
    int v = (t < NSB) ? bsum[t] : 0;
    s[t] = v;
    __syncthreads();
    for (int off = 1; off < 256; off <<= 1) {
        int cur = s[t];
        int add = (t >= off) ? s[t - off] : 0;
        __syncthreads();
        s[t] = cur + add;
        __syncthreads();
    }
    if (t < NSB) boff[t] = s[t] - v;
}

__global__ __launch_bounds__(256) void csr_setup_kernel(const int* __restrict__ deg,
                                                        const int* __restrict__ boff,
                                                        int* __restrict__ row_off,
                                                        float* __restrict__ dinv,
                                                        float* __restrict__ rdeg) {
    int b = blockIdx.x, t = threadIdx.x;
    int n = b * 256 + t;
    int v = (n < NN) ? deg[n] : 0;
    __shared__ int s[256];
    s[t] = v;
    __syncthreads();
    for (int off = 1; off < 256; off <<= 1) {
        int cur = s[t];
        int add = (t >= off) ? s[t - off] : 0;
        __syncthreads();
        s[t] = cur + add;
        __syncthreads();
    }
    int excl = s[t] - v + boff[b];
    if (n < NN) {
        row_off[n] = excl;
        float d = (float)v + 1.0f;
        dinv[n] = rsqrtf(d);
        rdeg[n] = sqrtf(d);
    }
    if (n == NN - 1) row_off[NN] = NE;
}

// partitioned, atomic-free scatter: only edges with dst in [d0,d1) write.
__global__ void scatter_pass_kernel(const int* __restrict__ src, const int* __restrict__ dst,
                                    const unsigned short* __restrict__ pos16,
                                    const int* __restrict__ row_off,
                                    int* __restrict__ csr_src, int d0, int d1) {
    int e = blockIdx.x * blockDim.x + threadIdx.x;
    if (e >= NE) return;
    int d = __builtin_nontemporal_load(&dst[e]);
    if (d < d0 || d >= d1) return;
    int s = __builtin_nontemporal_load(&src[e]);
    int p = (int)__builtin_nontemporal_load(&pos16[e]);
    csr_src[row_off[d] + p] = s;
}

// arow[n] = dinv[n] * (dinv[n] + sum_e dinv[src_e])
__global__ void arow_kernel(const int* __restrict__ row_off, const int* __restrict__ csr_src,
                            const float* __restrict__ dinv, float* __restrict__ arow) {
    int n = blockIdx.x * 256 + threadIdx.x;
    if (n >= NN) return;
    float dv = dinv[n];
    float s = dv;
    int e0 = row_off[n], e1 = row_off[n + 1];
    for (int i = e0; i < e1; ++i) s += dinv[csr_src[i]];
    arow[n] = dv * s;
}

// ---------------- BN stats over prelu(h_true) where h_true = rdeg * hs ----------------

__global__ __launch_bounds__(256) void bn_stats_kernel(const __half* __restrict__ h,
                                                       const float* __restrict__ rdeg,
                                                       const float* __restrict__ alpha_p,
                                                       float* __restrict__ stats) {
    float alpha = alpha_p[0];
    int tid = threadIdx.x;
    int c4 = (tid & 15) * 4;
    int rg = tid >> 4;
    float sx = 0, sy = 0, sz = 0, sw = 0;
    float qx = 0, qy = 0, qz = 0, qw = 0;
    for (int n = blockIdx.x * 16 + rg; n < NN; n += gridDim.x * 16) {
        float rd = rdeg[n];
        uint2 u = *(const uint2*)&h[(size_t)n * 64 + c4];
        float2 lo = up2(u.x), hi = up2(u.y);
        float a = lo.x >= 0.f ? lo.x : alpha * lo.x;
        float b = lo.y >= 0.f ? lo.y : alpha * lo.y;
        float c = hi.x >= 0.f ? hi.x : alpha * hi.x;
        float d = hi.y >= 0.f ? hi.y : alpha * hi.y;
        a *= rd; b *= rd; c *= rd; d *= rd;
        sx += a; sy += b; sz += c; sw += d;
        qx += a * a; qy += b * b; qz += c * c; qw += d * d;
    }
    __shared__ float ls[256 * 8];
    float* p = &ls[tid * 8];
    p[0] = sx; p[1] = sy; p[2] = sz; p[3] = sw;
    p[4] = qx; p[5] = qy; p[6] = qz; p[7] = qw;
    __syncthreads();
    if (tid < 128) {
        int cidx = tid >> 3;
        int j = tid & 7;
        float acc = 0.f;
        for (int r = 0; r < 16; ++r) acc += ls[(r * 16 + cidx) * 8 + j];
        int ch = cidx * 4 + (j & 3);
        if (j < 4) atomicAdd(&stats[ch], acc);
        else       atomicAdd(&stats[64 + ch], acc);
    }
}

// ---------------- CSR gather, full-row (8 lanes x 8 ch), software-pipelined 8-wide ----------------
// hs prescaled; sum = f(hs[r]) + sum_e f(hs[src_e]);  f = prelu if PRELU
// OUT 0: dv*sum + bias   OUT 1: dv*(dv*sum + bias)   OUT 2: dv*sum

template <bool PRELU, int OUT>
__global__ __launch_bounds__(256) void gather_kernel(const int* __restrict__ row_off,
                                                     const int* __restrict__ csr_src,
                                                     const float* __restrict__ dinv,
                                                     const float* __restrict__ bias,
                                                     const float* __restrict__ alpha_p,
                                                     const __half* __restrict__ hh,
                                                     __half* __restrict__ outp) {
    int tid = threadIdx.x;
    int r = blockIdx.x * 32 + (tid >> 3);
    int c = (tid & 7) * 8;
    if (r >= NN) return;
    float alpha = 0.f;
    if constexpr (PRELU) alpha = alpha_p[0];
    float acc[8];
    {
        uint4 u0 = *(const uint4*)&hh[(size_t)r * 64 + c];
        float2 p0 = up2(u0.x), p1 = up2(u0.y), p2 = up2(u0.z), p3 = up2(u0.w);
        acc[0] = p0.x; acc[1] = p0.y; acc[2] = p1.x; acc[3] = p1.y;
        acc[4] = p2.x; acc[5] = p2.y; acc[6] = p3.x; acc[7] = p3.y;
        if constexpr (PRELU) {
#pragma unroll
            for (int k = 0; k < 8; ++k) acc[k] = acc[k] >= 0.f ? acc[k] : alpha * acc[k];
        }
    }
    int beg = row_off[r];
    int end = row_off[r + 1];
    int nct = (end - beg + 7) >> 3;     // uniform 8-edge chunks, clamped + masked
    int base = beg;
    int q[8];
    if (nct > 0) {
#pragma unroll
        for (int j = 0; j < 8; ++j) {
            int pos = base + j;
            q[j] = csr_src[pos < end ? pos : end - 1];
        }
    }
    for (int it = 0; it < nct; ++it) {
        int s[8];
#pragma unroll
        for (int j = 0; j < 8; ++j) s[j] = q[j];
        int cbase = base;
        base += 8;
        if (it + 1 < nct) {
            // prefetch next chunk's indices: latency overlaps the h-loads below
#pragma unroll
            for (int j = 0; j < 8; ++j) {
                int pos = base + j;
                q[j] = csr_src[pos < end ? pos : end - 1];
            }
        }
        uint4 v[8];
#pragma unroll
        for (int j = 0; j < 8; ++j) v[j] = *(const uint4*)&hh[(size_t)s[j] * 64 + c];
#pragma unroll
        for (int j = 0; j < 8; ++j) {
            float m = (cbase + j < end) ? 1.f : 0.f;
            float2 p0 = up2(v[j].x), p1 = up2(v[j].y), p2 = up2(v[j].z), p3 = up2(v[j].w);
            float e[8] = {p0.x, p0.y, p1.x, p1.y, p2.x, p2.y, p3.x, p3.y};
            if constexpr (PRELU) {
#pragma unroll
                for (int k = 0; k < 8; ++k) e[k] = e[k] >= 0.f ? e[k] : alpha * e[k];
            }
#pragma unroll
            for (int k = 0; k < 8; ++k) acc[k] = fmaf(e[k], m, acc[k]);
        }
    }
    float dv = dinv[r];
    float o[8];
    if constexpr (OUT == 2) {
#pragma unroll
        for (int k = 0; k < 8; ++k) o[k] = dv * acc[k];
    } else {
        float4 b0 = *(const float4*)&bias[c];
        float4 b1 = *(const float4*)&bias[c + 4];
        float bl[8] = {b0.x, b0.y, b0.z, b0.w, b1.x, b1.y, b1.z, b1.w};
#pragma unroll
        for (int k = 0; k < 8; ++k) o[k] = dv * acc[k] + bl[k];
        if constexpr (OUT == 1) {
#pragma unroll
            for (int k = 0; k < 8; ++k) o[k] *= dv;
        }
    }
    uint4 ov;
    ov.x = pk2(o[0], o[1]);
    ov.y = pk2(o[2], o[3]);
    ov.z = pk2(o[4], o[5]);
    ov.w = pk2(o[6], o[7]);
    *(uint4*)&outp[(size_t)r * 64 + c] = ov;
}

// ---------------- pre-linear GEMM (f32 A): out16 = dinv * (x @ W + bias) ----------------

__global__ __launch_bounds__(256) void gemm_pre_kernel(const float* __restrict__ Af,
                                                       const float* __restrict__ W,
                                                       __half* __restrict__ outp,
                                                       const float* __restrict__ bias,
                                                       const float* __restrict__ dinv) {
    constexpr int K = 64, M = 64, BM = 128;
    constexpr int CG = M / 8;
    constexpr int RG = 256 / CG;
    constexpr int KP = K / 2;
    __shared__ unsigned Wh[KP * M];
    __shared__ unsigned Ahs[BM][KP + 4];
    int tid = threadIdx.x;
    for (int i = tid; i < KP * M; i += 256) {
        int kp = i / M, j = i % M;
        Wh[i] = pk2(W[(2 * kp) * M + j], W[(2 * kp + 1) * M + j]);
    }
    int r0 = blockIdx.x * BM;
    for (int i = tid; i < BM * (K / 4); i += 256) {
        int row = i / (K / 4);
        int k4 = (i % (K / 4)) * 4;
        int rr = r0 + row;
        if (rr > NN - 1) rr = NN - 1;
        float4 v = *(const float4*)&Af[(size_t)rr * K + k4];
        uint2 o;
        o.x = pk2(v.x, v.y);
        o.y = pk2(v.z, v.w);
        *(uint2*)&Ahs[row][k4 >> 1] = o;
    }
    __syncthreads();
    int cg = tid % CG, rg = tid / CG;
    int c = cg * 8;
    float acc[4][8];
#pragma unroll
    for (int r = 0; r < 4; ++r)
#pragma unroll
        for (int j = 0; j < 8; ++j) acc[r][j] = 0.f;
#pragma unroll 4
    for (int kp = 0; kp < KP; kp += 2) {
        uint2 a2[4];
#pragma unroll
        for (int r = 0; r < 4; ++r) a2[r] = *(const uint2*)&Ahs[rg + r * RG][kp];
#pragma unroll
        for (int kk = 0; kk < 2; ++kk) {
            const unsigned* wp = &Wh[(kp + kk) * M + c];
            uint4 w0 = *(const uint4*)wp;
            uint4 w1 = *(const uint4*)(wp + 4);
#pragma unroll
            for (int r = 0; r < 4; ++r) {
                unsigned av = kk ? a2[r].y : a2[r].x;
                acc[r][0] = fdot2u(av, w0.x, acc[r][0]);
                acc[r][1] = fdot2u(av, w0.y, acc[r][1]);
                acc[r][2] = fdot2u(av, w0.z, acc[r][2]);
                acc[r][3] = fdot2u(av, w0.w, acc[r][3]);
                acc[r][4] = fdot2u(av, w1.x, acc[r][4]);
                acc[r][5] = fdot2u(av, w1.y, acc[r][5]);
                acc[r][6] = fdot2u(av, w1.z, acc[r][6]);
                acc[r][7] = fdot2u(av, w1.w, acc[r][7]);
            }
        }
    }
    float4 b0 = *(const float4*)&bias[c];
    float4 b1 = *(const float4*)&bias[c + 4];
#pragma unroll
    for (int r = 0; r < 4; ++r) {
        int row = r0 + rg + r * RG;
        if (row < NN) {
            float sc = dinv[row];
            uint4 o;
            o.x = pk2((acc[r][0] + b0.x) * sc, (acc[r][1] + b0.y) * sc);
            o.y = pk2((acc[r][2] + b0.z) * sc, (acc[r][3] + b0.w) * sc);
            o.z = pk2((acc[r][4] + b1.x) * sc, (acc[r][5] + b1.y) * sc);
            o.w = pk2((acc[r][6] + b1.z) * sc, (acc[r][7] + b1.w) * sc);
            *(uint4*)&outp[(size_t)row * M + c] = o;
        }
    }
}

// ---------------- fused MFMA block MLP (in place on t16) ----------------
// t <- dinv * ( prelu( BN'(t) @ W1 + b1 ) @ W2 ), BM=64, 4 waves, U kept in LDS.
// A-frag: row=l&15, k=(l>>4)*8+j.  D: col=l&15, row=(l>>4)*4+reg.  [learn_hip m89/m97]

__global__ __launch_bounds__(256) void mfma_mlp_kernel(__half* __restrict__ t,
                                                       const float* __restrict__ W1,
                                                       const float* __restrict__ b1,
                                                       const float* __restrict__ W2,
                                                       const float* __restrict__ alpha2_p,
                                                       const float* __restrict__ stats,
                                                       const float* __restrict__ gamma,
                                                       const float* __restrict__ beta,
                                                       const float* __restrict__ arow,
                                                       const float* __restrict__ dinv) {
    __shared__ __align__(16) char smem[45056];
    auto Wt1 = (_Float16(*)[72])smem;             // [128][72]  (phase 2; 18432 B)
    auto Wt2 = (_Float16(*)[136])smem;            // [64][136]  aliases Wt1 (phase 3; 17408 B)
    auto At  = (_Float16(*)[72])(smem + 18432);   // [64][72]   (9216 B)
    auto Ut  = (_Float16(*)[136])(smem + 27648);  // [64][136]  (17408 B)
    __shared__ float scS[64], shS[64];
    int tid = threadIdx.x;
    if (tid < 64) {
        float mean = stats[tid] * (1.0f / NN);
        float var  = stats[64 + tid] * (1.0f / NN) - mean * mean;
        float sc = gamma[tid] * rsqrtf(var + BN_EPS);
        scS[tid] = sc;
        shS[tid] = beta[tid] - mean * sc;
    }
    for (int i = tid; i < 128 * 32; i += 256) {   // W1^T
        int j = i & 127;
        int k2 = i >> 7;
        *(unsigned*)&Wt1[j][2 * k2] = pk2(W1[(2 * k2) * 128 + j], W1[(2 * k2 + 1) * 128 + j]);
    }
    int r0 = blockIdx.x * 64;
    for (int i = tid; i < 64 * 16; i += 256) {    // A = BN'(t)
        int row = i >> 4;
        int k4 = (i & 15) * 4;
        int rr = r0 + row;
        if (rr > NN - 1) rr = NN - 1;
        uint2 uu = *(const uint2*)&t[(size_t)rr * 64 + k4];
        float2 lo = up2(uu.x), hi = up2(uu.y);
        float av = arow[rr];
        float vx = lo.x * scS[k4 + 0] + shS[k4 + 0] * av;
        float vy = lo.y * scS[k4 + 1] + shS[k4 + 1] * av;
        float vz = hi.x * scS[k4 + 2] + shS[k4 + 2] * av;
        float vw = hi.y * scS[k4 + 3] + shS[k4 + 3] * av;
        *(unsigned*)&At[row][k4]     = pk2(vx, vy);
        *(unsigned*)&At[row][k4 + 2] = pk2(vz, vw);
    }
    __syncthreads();
    int w = tid >> 6;
    int l = tid & 63;
    int lr = l & 15;
    int lk = (l >> 4) * 8;
    int rloc = w * 16 + (l >> 4) * 4;
    // phase 2: U = prelu(A @ W1 + b1)
    {
        f32x4 acc[8];
#pragma unroll
        for (int ct = 0; ct < 8; ++ct) acc[ct] = (f32x4){0.f, 0.f, 0.f, 0.f};
#pragma unroll
        for (int k0 = 0; k0 < 64; k0 += 32) {
            f16x8 a = *(const f16x8*)&At[w * 16 + lr][k0 + lk];
#pragma unroll
            for (int ct = 0; ct < 8; ++ct) {
                f16x8 b = *(const f16x8*)&Wt1[ct * 16 + lr][k0 + lk];
                acc[ct] = __builtin_amdgcn_mfma_f32_16x16x32_f16(a, b, acc[ct], 0, 0, 0);
            }
        }
        float alpha = alpha2_p[0];
#pragma unroll
        for (int ct = 0; ct < 8; ++ct) {
            int col = ct * 16 + lr;
            float bb = b1[col];
#pragma unroll
            for (int r = 0; r < 4; ++r) {
                float v = acc[ct][r] + bb;
                v = v >= 0.f ? v : alpha * v;
                Ut[rloc + r][col] = (_Float16)v;
            }
        }
    }
    __syncthreads();
    for (int i = tid; i < 64 * 64; i += 256) {    // W2^T into the Wt1 region
        int j = i & 63;
        int k2 = i >> 6;
        *(unsigned*)&Wt2[j][2 * k2] = pk2(W2[(2 * k2) * 64 + j], W2[(2 * k2 + 1) * 64 + j]);
    }
    __syncthreads();
    // phase 3: t = dinv * (U @ W2)
    {
        f32x4 acc[4];
#pragma unroll
        for (int ct = 0; ct < 4; ++ct) acc[ct] = (f32x4){0.f, 0.f, 0.f, 0.f};
#pragma unroll
        for (int k0 = 0; k0 < 128; k0 += 32) {
            f16x8 a = *(const f16x8*)&Ut[w * 16 + lr][k0 + lk];
#pragma unroll
            for (int ct = 0; ct < 4; ++ct) {
                f16x8 b = *(const f16x8*)&Wt2[ct * 16 + lr][k0 + lk];
                acc[ct] = __builtin_amdgcn_mfma_f32_16x16x32_f16(a, b, acc[ct], 0, 0, 0);
            }
        }
#pragma unroll
        for (int ct = 0; ct < 4; ++ct) {
            int col = ct * 16 + lr;
#pragma unroll
            for (int r = 0; r < 4; ++r) {
                int row = r0 + rloc + r;
                if (row < NN) t[(size_t)row * 64 + col] = __float2half(acc[ct][r] * dinv[row]);
            }
        }
    }
}

// ---------------- pool: one block per graph (batch sorted), fp16 in, f32 out ----------------

__global__ __launch_bounds__(256) void pool_seg_kernel(const __half* __restrict__ h,
                                                       const int* __restrict__ batch,
                                                       float* __restrict__ pooled) {
    int g = blockIdx.x;
    __shared__ int sbeg, send;
    int tid = threadIdx.x;
    if (tid == 0) {
        int lo = 0, hi = NN;
        while (lo < hi) { int mid = (lo + hi) >> 1; if (batch[mid] < g) lo = mid + 1; else hi = mid; }
        sbeg = lo;
        lo = 0; hi = NN;
        while (lo < hi) { int mid = (lo + hi) >> 1; if (batch[mid] < g + 1) lo = mid + 1; else hi = mid; }
        send = lo;
    }
    __syncthreads();
    int beg = sbeg, end = send;
    int c4 = (tid & 15) * 4;
    int rg = tid >> 4;
    float sx = 0, sy = 0, sz = 0, sw = 0;
    for (int n = beg + rg; n < end; n += 16) {
        uint2 u = *(const uint2*)&h[(size_t)n * 64 + c4];
        float2 lo = up2(u.x), hi = up2(u.y);
        sx += lo.x; sy += lo.y; sz += hi.x; sw += hi.y;
    }
    __shared__ float red[256 * 4];
    float* p = &red[tid * 4];
    p[0] = sx; p[1] = sy; p[2] = sz; p[3] = sw;
    __syncthreads();
    if (tid < 64) {
        int cg = tid >> 2;
        int j = tid & 3;
        float acc = 0.f;
        for (int r = 0; r < 16; ++r) acc += red[(r * 16 + cg) * 4 + j];
        float cnt = fmaxf((float)(end - beg), 1.0f);
        pooled[g * 64 + cg * 4 + j] = acc / cnt;
    }
}

// ---------------- head ----------------

__global__ __launch_bounds__(64) void head_stats_kernel(const float* __restrict__ pooled,
                                                        const float* __restrict__ gamma,
                                                        const float* __restrict__ beta,
                                                        float* __restrict__ headsc) {
    int ch = threadIdx.x;
    float s = 0.f, q = 0.f;
    for (int g = 0; g < 64; ++g) {
        float v = pooled[g * 64 + ch];
        s += v; q += v * v;
    }
    float mean = s * (1.0f / 64.0f);
    float var = q * (1.0f / 64.0f) - mean * mean;
    float sc = gamma[ch] * rsqrtf(var + BN_EPS);
    headsc[ch] = sc;
    headsc[64 + ch] = beta[ch] - mean * sc;
}

__global__ __launch_bounds__(256) void head_fc_kernel(const float* __restrict__ pooled,
                                                      const float* __restrict__ headsc,
                                                      const float* __restrict__ fc1w,
                                                      const float* __restrict__ fc1b,
                                                      const float* __restrict__ prelu_p,
                                                      const float* __restrict__ fc2w,
                                                      const float* __restrict__ fc2b,
                                                      float* __restrict__ out) {
    int g = blockIdx.x;
    int tid = threadIdx.x;
    __shared__ float pr[64];
    __shared__ float red[256];
    if (tid < 64) pr[tid] = pooled[g * 64 + tid] * headsc[tid] + headsc[64 + tid];
    __syncthreads();
    float alpha = prelu_p[0];
    float o1 = fc1b[tid];
    for (int k = 0; k < 64; ++k) o1 += pr[k] * fc1w[k * 256 + tid];
    o1 = o1 >= 0.f ? o1 : alpha * o1;
    for (int c = 0; c < NC; ++c) {
        red[tid] = o1 * fc2w[tid * NC + c];
        __syncthreads();
        for (int off = 128; off > 0; off >>= 1) {
            if (tid < off) red[tid] += red[tid + off];
            __syncthreads();
        }
        if (tid == 0) out[g * NC + c] = red[0] + fc2b[c];
        __syncthreads();
    }
}

// ---------------- launch ----------------

extern "C" void kernel_launch(void* const* d_in, const int* in_sizes, int n_in,
                              void* d_out, int out_size, void* d_ws, size_t ws_size,
                              hipStream_t stream) {
    const float* x       = (const float*)d_in[0];
    const int*   ei      = (const int*)d_in[1];
    const int*   batch   = (const int*)d_in[2];
    const float* pre_w   = (const float*)d_in[3];
    const float* pre_b   = (const float*)d_in[4];
    const float* bp1     = (const float*)d_in[5];
    const float* bng     = (const float*)d_in[6];
    const float* bnb     = (const float*)d_in[7];
    const float* bw1     = (const float*)d_in[8];
    const float* bb1     = (const float*)d_in[9];
    const float* bp2     = (const float*)d_in[10];
    const float* bw2     = (const float*)d_in[11];
    const float* bb2     = (const float*)d_in[12];
    const float* pgamma  = (const float*)d_in[13];
    const float* pbeta   = (const float*)d_in[14];
    const float* fc1w    = (const float*)d_in[15];
    const float* fc1b    = (const float*)d_in[16];
    const float* pprelu  = (const float*)d_in[17];
    const float* fc2w    = (const float*)d_in[18];
    const float* fc2b    = (const float*)d_in[19];

    const int* src = ei;
    const int* dst = ei + NE;

    __half* hA16 = (__half*)d_ws;                      // [NN,64] prescaled (hs)
    __half* t16  = hA16 + (size_t)NN * 64;             // [NN,64]
    float* dinv  = (float*)(t16 + (size_t)NN * 64);    // [NN]
    float* rdeg  = dinv + NN;                          // [NN]
    float* arow  = rdeg + NN;                          // [NN]
    float* stats = arow + NN;                          // [3*128] (zeroed)
    int*   deg   = (int*)(stats + 3 * 128);            // [NN]    (zeroed, adjacent to stats)
    float* pooledg = (float*)(deg + NN);               // [64*64]
    float* headsc  = pooledg + 64 * 64;                // [128]
    int*   csr_src = (int*)(headsc + 128);             // [NE]
    int*   row_off = csr_src + NE;                     // [NN+1]
    int*   bsum    = row_off + NN + 1;                 // [NSB]
    int*   boff    = bsum + NSB;                       // [NSB]
    unsigned short* pos16 = (unsigned short*)(boff + NSB);   // [NE]

    hipMemsetAsync(stats, 0, ((size_t)3 * 128 + NN) * 4, stream);

    deg_count_kernel<<<(NE + 255) / 256, 256, 0, stream>>>(dst, deg, pos16);
    block_sum_kernel<<<NSB, 256, 0, stream>>>(deg, bsum);
    bsum_scan_kernel<<<1, 256, 0, stream>>>(bsum, boff);
    csr_setup_kernel<<<NSB, 256, 0, stream>>>(deg, boff, row_off, dinv, rdeg);
    for (int p = 0; p < 2; ++p) {
        int d0 = p * 25000;
        int d1 = (p == 1) ? NN : d0 + 25000;
        scatter_pass_kernel<<<(NE + 255) / 256, 256, 0, stream>>>(
            src, dst, pos16, row_off, csr_src, d0, d1);
    }
    arow_kernel<<<(NN + 255) / 256, 256, 0, stream>>>(row_off, csr_src, dinv, arow);

    // pre-linear: hA16 = dinv * (x @ pre_w + pre_b)
    gemm_pre_kernel<<<(NN + 127) / 128, 256, 0, stream>>>(x, pre_w, hA16, pre_b, dinv);

    int ggrid = (NN + 31) / 32;
    for (int i = 0; i < 3; ++i) {
        const float* a1 = bp1 + i;
        const float* a2 = bp2 + i;
        const float* gm = bng + i * 64;
        const float* bt = bnb + i * 64;
        const float* w1 = bw1 + (size_t)i * 64 * 128;
        const float* b1 = bb1 + i * 128;
        const float* w2 = bw2 + (size_t)i * 128 * 64;
        const float* b2 = bb2 + i * 64;
        float* st = stats + i * 128;

        bn_stats_kernel<<<256, 256, 0, stream>>>(hA16, rdeg, a1, st);
        // t16 = A_hat @ prelu(h)  (true scale)
        gather_kernel<true, 2><<<ggrid, 256, 0, stream>>>(
            row_off, csr_src, dinv, nullptr, a1, hA16, t16);
        // t16 <- dinv * ( prelu( BN'(t16) @ w1 + b1 ) @ w2 )  (fused MFMA MLP, in place)
        mfma_mlp_kernel<<<(NN + 63) / 64, 256, 0, stream>>>(
            t16, w1, b1, w2, a2, st, gm, bt, arow, dinv);
        // hA16 = A_hat @ t16 + b2  (prescaled except last block)
        if (i < 2) {
            gather_kernel<false, 1><<<ggrid, 256, 0, stream>>>(
                row_off, csr_src, dinv, b2, nullptr, t16, hA16);
        } else {
            gather_kernel<false, 0><<<ggrid, 256, 0, stream>>>(
                row_off, csr_src, dinv, b2, nullptr, t16, hA16);
        }
    }

    pool_seg_kernel<<<NG, 256, 0, stream>>>(hA16, batch, pooledg);
    head_stats_kernel<<<1, 64, 0, stream>>>(pooledg, pgamma, pbeta, headsc);
    head_fc_kernel<<<NG, 256, 0, stream>>>(pooledg, headsc, fc1w, fc1b, pprelu,
                                           fc2w, fc2b, (float*)d_out);
}